// Round 1
// baseline (2977.089 us; speedup 1.0000x reference)
//
#include <hip/hip_runtime.h>
#include <cstdint>
#include <cstddef>

// Problem dims
#define Bsz 512
#define Nsq 50
#define Hd  256
#define MEMN 8
#define VM1 40000
static constexpr float SCALE_C = 0.0625f;   // 1/sqrt(256)
static constexpr float NEG_C   = -1.0e12f;

__device__ __forceinline__ float sigmoidf_(float x) { return 1.0f / (1.0f + expf(-x)); }

// ---------------------------------------------------------------- TAB (50x256)
__global__ void build_tab(float* __restrict__ TAB) {
  int idx = blockIdx.x * 256 + threadIdx.x;   // 50*256
  int pos = idx >> 8, j = idx & 255;
  int pair = j >> 1;
  float expo = (2.0f * (float)pair) / 256.0f;
  float inv = powf(10000.0f, -expo);
  float ang = (float)pos * inv;
  TAB[idx] = (j & 1) ? cosf(ang) : sinf(ang);
}

// ------------------------------------------------- last[b], sr_l_1 = seq1[b,last]
__global__ __launch_bounds__(256) void last_srl_kernel(const int* __restrict__ mask,
    const float* __restrict__ seq1, int* __restrict__ lastp, float* __restrict__ srl) {
  int b = blockIdx.x, tid = threadIdx.x;
  __shared__ int ls;
  if (tid == 0) {
    int c = 0;
    for (int t = 0; t < Nsq; ++t) c += mask[b * Nsq + t];
    ls = c - 1;
    lastp[b] = c - 1;
  }
  __syncthreads();
  srl[b * Hd + tid] = seq1[((size_t)b * Nsq + ls) * Hd + tid];
}

// ---------------------------------------------------------------- fp32 GEMM
// C[M,N] = A[M,K] @ (BT ? B[N,K]^T : B[K,N]) (+ bias[N])
// tile 128(M) x 64(N), K-step 16; 256 threads, 8x4 per thread.
// Requires M%128==0, N%64==0, K%16==0 (all shapes here satisfy this).
template <int BT, int BIAS>
__global__ __launch_bounds__(256) void gemm_tile(const float* __restrict__ A,
    const float* __restrict__ B, const float* __restrict__ bias,
    float* __restrict__ C, int M, int N, int K) {
  __shared__ float As[16][132];
  __shared__ float Bs[16][68];
  int bm = blockIdx.y * 128, bn = blockIdx.x * 64;
  int tid = threadIdx.x;
  int tm = (tid >> 4) << 3;   // 0..120
  int tn = (tid & 15) << 2;   // 0..60
  float acc[8][4] = {};
  for (int k0 = 0; k0 < K; k0 += 16) {
#pragma unroll
    for (int u = 0; u < 8; ++u) {
      int i = tid + u * 256;            // 0..2047
      int kk = i & 15, m = i >> 4;
      As[kk][m] = A[(size_t)(bm + m) * K + (k0 + kk)];
    }
#pragma unroll
    for (int u = 0; u < 4; ++u) {
      int i = tid + u * 256;            // 0..1023
      if (BT) {
        int kk = i & 15, n = i >> 4;
        Bs[kk][n] = B[(size_t)(bn + n) * K + (k0 + kk)];
      } else {
        int n = i & 63, kk = i >> 6;
        Bs[kk][n] = B[(size_t)(k0 + kk) * N + (bn + n)];
      }
    }
    __syncthreads();
#pragma unroll
    for (int kk = 0; kk < 16; ++kk) {
      float a[8], bb[4];
#pragma unroll
      for (int r = 0; r < 8; ++r) a[r] = As[kk][tm + r];
#pragma unroll
      for (int c = 0; c < 4; ++c) bb[c] = Bs[kk][tn + c];
#pragma unroll
      for (int r = 0; r < 8; ++r)
#pragma unroll
        for (int c = 0; c < 4; ++c) acc[r][c] += a[r] * bb[c];
    }
    __syncthreads();
  }
#pragma unroll
  for (int r = 0; r < 8; ++r) {
    size_t row = (size_t)(bm + tm + r) * N + bn;
#pragma unroll
    for (int c = 0; c < 4; ++c) {
      float v = acc[r][c];
      if (BIAS) v += bias[bn + tn + c];
      C[row + tn + c] = v;
    }
  }
}

// ---------------------------------------------------------------- misc elementwise
__global__ void add_tab0(float* __restrict__ q) {           // q1_1 += TAB[0]
  int idx = blockIdx.x * 256 + threadIdx.x;                 // 512*256
  q[idx] += (float)(threadIdx.x & 1);                       // sin(0)=0, cos(0)=1
}

__global__ void transpose_whh(const float* __restrict__ w, float* __restrict__ wT) {
  int idx = blockIdx.x * 256 + threadIdx.x;                 // 256*768, idx = k*768+r
  int k = idx / 768, r = idx % 768;
  wT[idx] = w[r * 256 + k];
}

__global__ void mask_mul(const float* __restrict__ x, const int* __restrict__ m,
                         float* __restrict__ y) {
  int idx = blockIdx.x * 256 + threadIdx.x;                 // B*N*H
  y[idx] = m[idx >> 8] ? x[idx] : 0.0f;
}

__global__ void add_pe3(float* __restrict__ q, float* __restrict__ k, float* __restrict__ v,
                        const float* __restrict__ TAB, const int* __restrict__ lastp) {
  int idx = blockIdx.x * 256 + threadIdx.x;                 // B*N*H
  int j = idx & 255, bt = idx >> 8;
  int b = bt / Nsq, t = bt - b * Nsq;
  int d = abs(t - lastp[b]);
  float pe = TAB[d * 256 + j];
  q[idx] += pe; k[idx] += pe; v[idx] += pe;
}

__global__ void relu_add(float* __restrict__ a, const float* __restrict__ b) {
  int idx = blockIdx.x * 256 + threadIdx.x;
  a[idx] = fmaxf(a[idx] + b[idx], 0.0f);
}

// ---------------------------------------------------------------- GRU layer
// grid 128 blocks x 768 threads; block owns 4 batch rows for all 50 steps.
__global__ __launch_bounds__(768) void gru_layer_kernel(const float* __restrict__ gi,
    const float* __restrict__ whhT, const float* __restrict__ bhh, float* __restrict__ ys) {
  __shared__ float h[4][256];
  __shared__ float ghs[768][5];     // [g*256+j][row], pad 5 vs bank conflicts
  int tid = threadIdx.x;
  int b0 = blockIdx.x * 4;
  for (int i = tid; i < 1024; i += 768) h[i >> 8][i & 255] = 0.0f;
  float bh = bhh[tid];
  __syncthreads();
  for (int t = 0; t < Nsq; ++t) {
    float a0 = 0.f, a1 = 0.f, a2 = 0.f, a3 = 0.f;
#pragma unroll 4
    for (int k = 0; k < 256; ++k) {
      float wv = whhT[k * 768 + tid];
      a0 += wv * h[0][k]; a1 += wv * h[1][k]; a2 += wv * h[2][k]; a3 += wv * h[3][k];
    }
    ghs[tid][0] = a0 + bh; ghs[tid][1] = a1 + bh; ghs[tid][2] = a2 + bh; ghs[tid][3] = a3 + bh;
    __syncthreads();
    for (int idx = tid; idx < 1024; idx += 768) {
      int r = idx >> 8, jj = idx & 255;
      int bb = b0 + r;
      const float* gib = gi + ((size_t)bb * Nsq + t) * 768;
      float ir = gib[jj], iz = gib[256 + jj], inn = gib[512 + jj];
      float hr = ghs[jj][r], hz = ghs[256 + jj][r], hn = ghs[512 + jj][r];
      float rr = sigmoidf_(ir + hr);
      float zz = sigmoidf_(iz + hz);
      float nn = tanhf(inn + rr * hn);
      float h2 = (1.0f - zz) * nn + zz * h[r][jj];
      h[r][jj] = h2;
      ys[((size_t)bb * Nsq + t) * 256 + jj] = h2;
    }
    __syncthreads();
  }
}

// ---------------------------------------------------------------- attention 1 (causal self)
__global__ __launch_bounds__(256) void attn1_kernel(const float* __restrict__ q1,
    const float* __restrict__ k1, const float* __restrict__ v1,
    const int* __restrict__ mask, float* __restrict__ out) {
  int b = blockIdx.x, tid = threadIdx.x;
  __shared__ float Ks[50][257];
  __shared__ float qs[256];
  __shared__ float ps[64];
  __shared__ float part[64][5];
  __shared__ int msk[50];
  const float* kb = k1 + (size_t)b * Nsq * Hd;
  for (int i = tid; i < 50 * 256; i += 256) Ks[i >> 8][i & 255] = kb[i];
  if (tid < 50) msk[tid] = mask[b * Nsq + tid];
  __syncthreads();
  const float* vb = v1 + (size_t)b * Nsq * Hd;
  for (int t = 0; t < Nsq; ++t) {
    qs[tid] = q1[((size_t)b * Nsq + t) * Hd + tid];
    __syncthreads();
    int j = tid & 63, w = tid >> 6;
    float p = 0.0f;
    if (j < 50) {
      const float* kr = &Ks[j][w * 64];
      const float* qr = &qs[w * 64];
#pragma unroll
      for (int hh = 0; hh < 64; ++hh) p += qr[hh] * kr[hh];
    }
    part[j][w] = p;
    __syncthreads();
    if (tid < 64) {
      float s = part[tid][0] + part[tid][1] + part[tid][2] + part[tid][3];
      bool ok = (tid < 50) && (tid <= t) && (msk[tid] != 0);
      s = ok ? s * SCALE_C : NEG_C;
      float m = s;
      for (int off = 32; off; off >>= 1) m = fmaxf(m, __shfl_xor(m, off));
      float e = expf(s - m);
      float sum = e;
      for (int off = 32; off; off >>= 1) sum += __shfl_xor(sum, off);
      ps[tid] = e / sum;
    }
    __syncthreads();
    float o = 0.0f;
    for (int jj = 0; jj <= t; ++jj) o += ps[jj] * vb[jj * 256 + tid];
    if (!msk[t]) o = 0.0f;
    out[((size_t)b * Nsq + t) * Hd + tid] = o;
    __syncthreads();
  }
}

// ---------------------------------------------------------------- attention 2 (mem + causal)
__global__ __launch_bounds__(256) void attn2_kernel(const float* __restrict__ q1,
    const float* __restrict__ k2, const float* __restrict__ v2,
    const float* __restrict__ memk, const float* __restrict__ memv,
    const int* __restrict__ mask, float* __restrict__ out) {
  int b = blockIdx.x, tid = threadIdx.x;
  __shared__ float Ks[58][257];
  __shared__ float qs[256];
  __shared__ float ps[64];
  __shared__ float part[64][5];
  __shared__ int msk[50];
  for (int i = tid; i < 58 * 256; i += 256) {
    int row = i >> 8, col = i & 255;
    Ks[row][col] = (row < 8) ? memk[row * 256 + col]
                             : k2[((size_t)b * Nsq + (row - 8)) * 256 + col];
  }
  if (tid < 50) msk[tid] = mask[b * Nsq + tid];
  __syncthreads();
  for (int t = 0; t < Nsq; ++t) {
    qs[tid] = q1[((size_t)b * Nsq + t) * Hd + tid];
    __syncthreads();
    int j = tid & 63, w = tid >> 6;
    float p = 0.0f;
    if (j < 58) {
      const float* kr = &Ks[j][w * 64];
      const float* qr = &qs[w * 64];
#pragma unroll
      for (int hh = 0; hh < 64; ++hh) p += qr[hh] * kr[hh];
    }
    part[j][w] = p;
    __syncthreads();
    if (tid < 64) {
      float s = part[tid][0] + part[tid][1] + part[tid][2] + part[tid][3];
      bool ok;
      if (tid < 8) ok = true;
      else if (tid < 58) ok = ((tid - 8) <= t) && (msk[tid - 8] != 0);
      else ok = false;
      s = ok ? s * SCALE_C : NEG_C;
      float m = s;
      for (int off = 32; off; off >>= 1) m = fmaxf(m, __shfl_xor(m, off));
      float e = expf(s - m);
      float sum = e;
      for (int off = 32; off; off >>= 1) sum += __shfl_xor(sum, off);
      ps[tid] = e / sum;
    }
    __syncthreads();
    float o = 0.0f;
    int jmax = min(57, t + 8);
    for (int jj = 0; jj <= jmax; ++jj) {
      float vv = (jj < 8) ? memv[jj * 256 + tid]
                          : v2[((size_t)b * Nsq + (jj - 8)) * 256 + tid];
      o += ps[jj] * vv;
    }
    if (!msk[t]) o = 0.0f;
    out[((size_t)b * Nsq + t) * Hd + tid] = o;
    __syncthreads();
  }
}

// ---------------------------------------------------------------- alpha + sess (→ sesscat)
__global__ __launch_bounds__(256) void alpha_sess_kernel(const float* __restrict__ att,
    const float* __restrict__ W3, const float* __restrict__ q11,
    const float* __restrict__ se1, const int* __restrict__ mask,
    const float* __restrict__ srl, float* __restrict__ sesscat) {
  int b = blockIdx.x, tid = threadIdx.x;
  __shared__ float red[256];
  __shared__ float ash[50];
  red[tid] = q11[b * Hd + tid] * W3[256 + tid];
  __syncthreads();
  for (int s = 128; s; s >>= 1) { if (tid < s) red[tid] += red[tid + s]; __syncthreads(); }
  float cq = red[0];
  float aval = 0.0f;
  if (tid < 50) {
    float s = cq;
    const float* ar = att + ((size_t)b * Nsq + tid) * Hd;
    for (int hh = 0; hh < 256; ++hh) s += ar[hh] * W3[hh];
    aval = mask[b * Nsq + tid] ? s : NEG_C;
  }
  if (tid < 64) {
    float s = (tid < 50) ? aval : NEG_C;
    float m = s;
    for (int off = 32; off; off >>= 1) m = fmaxf(m, __shfl_xor(m, off));
    float e = expf(s - m);
    float sum = e;
    for (int off = 32; off; off >>= 1) sum += __shfl_xor(sum, off);
    if (tid < 50) ash[tid] = e / sum;
  }
  __syncthreads();
  float acc = 0.0f;
  const float* se = se1 + (size_t)b * Nsq * Hd;
  for (int t = 0; t < Nsq; ++t) acc += ash[t] * se[t * 256 + tid];
  sesscat[(size_t)b * 512 + tid] = acc;
  sesscat[(size_t)b * 512 + 256 + tid] = srl[b * Hd + tid];
}

// ---------------------------------------------------------------- beta + boundary
__global__ __launch_bounds__(256) void beta_kernel(const float* __restrict__ sess2,
    const float* __restrict__ Wt1, const float* __restrict__ bt1,
    const float* __restrict__ Wt2, float* __restrict__ beta, float* __restrict__ bnd) {
  int b = blockIdx.x, tid = threadIdx.x;
  __shared__ float xs[256];
  __shared__ float r0[256], r1[256];
  xs[tid] = sess2[b * Hd + tid];
  __syncthreads();
  float hsum = bt1[tid];
  for (int k = 0; k < 256; ++k) hsum += xs[k] * Wt1[k * 256 + tid];
  float hid = fmaxf(hsum, 0.0f);
  r0[tid] = hid * Wt2[tid * 2 + 0];
  r1[tid] = hid * Wt2[tid * 2 + 1];
  __syncthreads();
  for (int s = 128; s; s >>= 1) {
    if (tid < s) { r0[tid] += r0[tid + s]; r1[tid] += r1[tid + s]; }
    __syncthreads();
  }
  if (tid == 0) {
    float t0 = r0[0], t1 = r1[0];
    float m = fmaxf(t0, t1);
    float e0 = expf(t0 - m), e1 = expf(t1 - m);
    float bb0 = e0 / (e0 + e1), bb1 = e1 / (e0 + e1);
    beta[b * 2] = bb0; beta[b * 2 + 1] = bb1;
    atomicAdd(bnd, fabsf(bb0 - bb1) * (1.0f / 512.0f));
  }
}

// ---------------------------------------------------------------- score softmax stats
__global__ __launch_bounds__(256) void score_stats_kernel(const float* __restrict__ score,
    const int* __restrict__ flag, float* __restrict__ stats) {
  int b = blockIdx.x, tid = threadIdx.x;
  float mi = -INFINITY, si = 0.0f, me = -INFINITY, se = 0.0f;
  const float* sr = score + (size_t)b * VM1;
  const int* fr = flag + (size_t)b * VM1;
  for (int i = tid; i < VM1; i += 256) {
    float s = sr[i];
    int f = fr[i];
    float vi = f ? s : NEG_C;
    float ve = f ? NEG_C : s;
    float mni = fmaxf(mi, vi); si = si * expf(mi - mni) + expf(vi - mni); mi = mni;
    float mne = fmaxf(me, ve); se = se * expf(me - mne) + expf(ve - mne); me = mne;
  }
  __shared__ float red[256];
  red[tid] = mi; __syncthreads();
  for (int s = 128; s; s >>= 1) { if (tid < s) red[tid] = fmaxf(red[tid], red[tid + s]); __syncthreads(); }
  float Mi = red[0]; __syncthreads();
  red[tid] = si * expf(mi - Mi); __syncthreads();
  for (int s = 128; s; s >>= 1) { if (tid < s) red[tid] += red[tid + s]; __syncthreads(); }
  float Si = red[0]; __syncthreads();
  red[tid] = me; __syncthreads();
  for (int s = 128; s; s >>= 1) { if (tid < s) red[tid] = fmaxf(red[tid], red[tid + s]); __syncthreads(); }
  float Me = red[0]; __syncthreads();
  red[tid] = se * expf(me - Me); __syncthreads();
  for (int s = 128; s; s >>= 1) { if (tid < s) red[tid] += red[tid + s]; __syncthreads(); }
  float Se = red[0];
  if (tid == 0) { stats[b * 4] = Mi; stats[b * 4 + 1] = Si; stats[b * 4 + 2] = Me; stats[b * 4 + 3] = Se; }
}

// ---------------------------------------------------------------- final (in-place on score)
__global__ void final_kernel(float* __restrict__ score, const int* __restrict__ flag,
                             const float* __restrict__ stats, const float* __restrict__ beta) {
  int idx = blockIdx.x * 256 + threadIdx.x;                 // 20,480,000 exact
  int b = idx / VM1;
  float s = score[idx];
  int f = flag[idx];
  float vi = f ? s : NEG_C;
  float ve = f ? NEG_C : s;
  float fin = beta[b * 2] * expf(vi - stats[b * 4]) / stats[b * 4 + 1]
            + beta[b * 2 + 1] * expf(ve - stats[b * 4 + 2]) / stats[b * 4 + 3];
  score[idx] = fin;
}

// ================================================================ launch
extern "C" void kernel_launch(void* const* d_in, const int* in_sizes, int n_in,
                              void* d_out, int out_size, void* d_ws, size_t ws_size,
                              hipStream_t stream) {
  const float* seq1  = (const float*)d_in[0];
  const float* seq2  = (const float*)d_in[1];
  const int*   mask  = (const int*)d_in[2];
  const int*   iflag = (const int*)d_in[3];
  const float* wih0  = (const float*)d_in[4];
  const float* whh0  = (const float*)d_in[5];
  const float* bih0  = (const float*)d_in[6];
  const float* bhh0  = (const float*)d_in[7];
  const float* wih1  = (const float*)d_in[8];
  const float* whh1  = (const float*)d_in[9];
  const float* bih1  = (const float*)d_in[10];
  const float* bhh1  = (const float*)d_in[11];
  const float* Wq1   = (const float*)d_in[12];
  const float* Wk1   = (const float*)d_in[13];
  const float* Wv1   = (const float*)d_in[14];
  // d_in[15] Wq2 unused by reference
  const float* Wk2   = (const float*)d_in[16];
  const float* Wv2   = (const float*)d_in[17];
  const float* Wffn1 = (const float*)d_in[18];
  const float* bffn1 = (const float*)d_in[19];
  const float* Wffn2 = (const float*)d_in[20];
  const float* bffn2 = (const float*)d_in[21];
  const float* Wone  = (const float*)d_in[22];
  const float* bone  = (const float*)d_in[23];
  const float* W3    = (const float*)d_in[24];
  const float* Wtr   = (const float*)d_in[25];
  const float* btr   = (const float*)d_in[26];
  const float* Wt1   = (const float*)d_in[27];
  const float* bt1   = (const float*)d_in[28];
  const float* Wt2   = (const float*)d_in[29];
  const float* memk  = (const float*)d_in[30];
  const float* memv  = (const float*)d_in[31];
  const float* emb1  = (const float*)d_in[32];
  float* out = (float*)d_out;

  // Workspace layout (floats). Total required ≈ 59.7M floats ≈ 239 MB.
  float* ws = (float*)d_ws;
  float* TAB    = ws;                          // 12800
  int*   lastp  = (int*)(ws + 12800);          // 512
  float* srl    = ws + 13312;                  // 131072
  float* q11    = ws + 144384;                 // 131072
  float* whhT0  = ws + 275456;                 // 196608
  float* whhT1  = ws + 472064;                 // 196608
  float* gi     = ws + 668672;                 // 19,660,800  (later q1|k1|v1)
  float* bufA   = ws + 20329472;               // 6,553,600   s2a / ao1
  float* bufB   = ws + 26883072;               // 6,553,600   s2  / ao2
  float* se1    = ws + 33436672;               // 6,553,600
  float* bufC   = ws + 39990272;               // 6,553,600   se2 / att
  float* k2buf  = ws + 46543872;               // 6,553,600   k2  / a2p
  float* v2buf  = ws + 53097472;               // 6,553,600   v2  / tail scratch
  float* q1 = gi;
  float* k1 = gi + 6553600;
  float* v1 = gi + 13107200;
  float* sesscat = v2buf;                      // 262144  (v2 dead after attn2)
  float* sess2   = v2buf + 262144;             // 131072
  float* betab   = v2buf + 393216;             // 1024
  float* stats   = v2buf + 394240;             // 2048
  float* bnd = out + (size_t)Bsz * VM1;        // boundary slot = last output element

  // ---- positional table / last / sr_l / q1_1
  build_tab<<<50, 256, 0, stream>>>(TAB);
  last_srl_kernel<<<Bsz, 256, 0, stream>>>(mask, seq1, lastp, srl);
  gemm_tile<0, 1><<<dim3(4, 4), 256, 0, stream>>>(srl, Wone, bone, q11, 512, 256, 256);
  add_tab0<<<512, 256, 0, stream>>>(q11);

  // ---- GRU (2 layers)
  transpose_whh<<<768, 256, 0, stream>>>(whh0, whhT0);
  transpose_whh<<<768, 256, 0, stream>>>(whh1, whhT1);
  gemm_tile<1, 1><<<dim3(12, 200), 256, 0, stream>>>(seq2, wih0, bih0, gi, 25600, 768, 256);
  gru_layer_kernel<<<128, 768, 0, stream>>>(gi, whhT0, bhh0, bufA);
  gemm_tile<1, 1><<<dim3(12, 200), 256, 0, stream>>>(bufA, wih1, bih1, gi, 25600, 768, 256);
  gru_layer_kernel<<<128, 768, 0, stream>>>(gi, whhT1, bhh1, bufB);

  // ---- masked sequences
  mask_mul<<<25600, 256, 0, stream>>>(seq1, mask, se1);
  mask_mul<<<25600, 256, 0, stream>>>(bufB, mask, bufC);   // se2

  // ---- projections
  gemm_tile<0, 0><<<dim3(4, 200), 256, 0, stream>>>(bufC, Wk2, nullptr, k2buf, 25600, 256, 256);
  gemm_tile<0, 0><<<dim3(4, 200), 256, 0, stream>>>(bufC, Wv2, nullptr, v2buf, 25600, 256, 256);
  gemm_tile<0, 0><<<dim3(4, 200), 256, 0, stream>>>(se1, Wq1, nullptr, q1, 25600, 256, 256);
  gemm_tile<0, 0><<<dim3(4, 200), 256, 0, stream>>>(se1, Wk1, nullptr, k1, 25600, 256, 256);
  gemm_tile<0, 0><<<dim3(4, 200), 256, 0, stream>>>(se1, Wv1, nullptr, v1, 25600, 256, 256);
  add_pe3<<<25600, 256, 0, stream>>>(q1, k1, v1, TAB, lastp);

  // ---- attentions
  attn1_kernel<<<Bsz, 256, 0, stream>>>(q1, k1, v1, mask, bufA);
  attn2_kernel<<<Bsz, 256, 0, stream>>>(q1, k2buf, v2buf, memk, memv, mask, bufB);
  gemm_tile<0, 1><<<dim3(4, 200), 256, 0, stream>>>(bufA, Wffn1, bffn1, bufC, 25600, 256, 256);
  gemm_tile<0, 1><<<dim3(4, 200), 256, 0, stream>>>(bufB, Wffn2, bffn2, k2buf, 25600, 256, 256);
  relu_add<<<25600, 256, 0, stream>>>(bufC, k2buf);        // att = relu(att1+att2)

  // ---- pooling + session vector
  alpha_sess_kernel<<<Bsz, 256, 0, stream>>>(bufC, W3, q11, se1, mask, srl, sesscat);
  gemm_tile<0, 1><<<dim3(4, 4), 256, 0, stream>>>(sesscat, Wtr, btr, sess2, 512, 256, 512);

  // ---- tail gating (boundary) + scoring
  hipMemsetAsync(bnd, 0, 4, stream);
  beta_kernel<<<Bsz, 256, 0, stream>>>(sess2, Wt1, bt1, Wt2, betab, bnd);
  gemm_tile<1, 0><<<dim3(625, 4), 256, 0, stream>>>(sess2, emb1 + 256, nullptr, out, 512, VM1, 256);
  score_stats_kernel<<<Bsz, 256, 0, stream>>>(out, iflag, stats);
  final_kernel<<<80000, 256, 0, stream>>>(out, iflag, stats, betab);

  (void)in_sizes; (void)n_in; (void)out_size; (void)ws_size;
}

// Round 2
// 2358.577 us; speedup vs baseline: 1.2622x; 1.2622x over previous
//
#include <hip/hip_runtime.h>
#include <hip/hip_bf16.h>
#include <cstdint>
#include <cstddef>

// Problem dims
#define Bsz 512
#define Nsq 50
#define Hd  256
#define VM1 40000
static constexpr float SCALE_C = 0.0625f;   // 1/sqrt(256)
static constexpr float NEG_C   = -1.0e12f;

typedef __attribute__((ext_vector_type(8))) short bf16x8;
typedef __attribute__((ext_vector_type(4))) float f32x4;

__device__ __forceinline__ float sigmoidf_(float x) { return 1.0f / (1.0f + __expf(-x)); }
__device__ __forceinline__ float tanh_fast(float x) {
  float t = fminf(fmaxf(2.0f * x, -60.0f), 60.0f);
  float e = __expf(t);
  return (e - 1.0f) / (e + 1.0f);
}
__device__ __forceinline__ ushort f2b(float x) {   // fp32 -> bf16 (RNE)
  union { float f; uint32_t u; } c; c.f = x;
  uint32_t r = (c.u + 0x7fffu + ((c.u >> 16) & 1u)) >> 16;
  return (ushort)r;
}

// ---------------------------------------------------------------- TAB (50x256)
__global__ void build_tab(float* __restrict__ TAB) {
  int idx = blockIdx.x * 256 + threadIdx.x;
  int pos = idx >> 8, j = idx & 255;
  int pair = j >> 1;
  float expo = (2.0f * (float)pair) / 256.0f;
  float inv = powf(10000.0f, -expo);
  float ang = (float)pos * inv;
  TAB[idx] = (j & 1) ? cosf(ang) : sinf(ang);
}

// ------------------------------------------------- last[b], sr_l_1 = seq1[b,last]
__global__ __launch_bounds__(256) void last_srl_kernel(const int* __restrict__ mask,
    const float* __restrict__ seq1, int* __restrict__ lastp, float* __restrict__ srl) {
  int b = blockIdx.x, tid = threadIdx.x;
  __shared__ int ls;
  if (tid == 0) {
    int c = 0;
    for (int t = 0; t < Nsq; ++t) c += mask[b * Nsq + t];
    ls = c - 1;
    lastp[b] = c - 1;
  }
  __syncthreads();
  srl[b * Hd + tid] = seq1[((size_t)b * Nsq + ls) * Hd + tid];
}

// ---------------------------------------------------------------- fp32 GEMM (small shapes only)
template <int BT, int BIAS>
__global__ __launch_bounds__(256) void gemm_tile(const float* __restrict__ A,
    const float* __restrict__ B, const float* __restrict__ bias,
    float* __restrict__ C, int M, int N, int K) {
  __shared__ float As[16][132];
  __shared__ float Bs[16][68];
  int bm = blockIdx.y * 128, bn = blockIdx.x * 64;
  int tid = threadIdx.x;
  int tm = (tid >> 4) << 3;
  int tn = (tid & 15) << 2;
  float acc[8][4] = {};
  for (int k0 = 0; k0 < K; k0 += 16) {
#pragma unroll
    for (int u = 0; u < 8; ++u) {
      int i = tid + u * 256;
      int kk = i & 15, m = i >> 4;
      As[kk][m] = A[(size_t)(bm + m) * K + (k0 + kk)];
    }
#pragma unroll
    for (int u = 0; u < 4; ++u) {
      int i = tid + u * 256;
      if (BT) {
        int kk = i & 15, n = i >> 4;
        Bs[kk][n] = B[(size_t)(bn + n) * K + (k0 + kk)];
      } else {
        int n = i & 63, kk = i >> 6;
        Bs[kk][n] = B[(size_t)(k0 + kk) * N + (bn + n)];
      }
    }
    __syncthreads();
#pragma unroll
    for (int kk = 0; kk < 16; ++kk) {
      float a[8], bb[4];
#pragma unroll
      for (int r = 0; r < 8; ++r) a[r] = As[kk][tm + r];
#pragma unroll
      for (int c = 0; c < 4; ++c) bb[c] = Bs[kk][tn + c];
#pragma unroll
      for (int r = 0; r < 8; ++r)
#pragma unroll
        for (int c = 0; c < 4; ++c) acc[r][c] += a[r] * bb[c];
    }
    __syncthreads();
  }
#pragma unroll
  for (int r = 0; r < 8; ++r) {
    size_t row = (size_t)(bm + tm + r) * N + bn;
#pragma unroll
    for (int c = 0; c < 4; ++c) {
      float v = acc[r][c];
      if (BIAS) v += bias[bn + tn + c];
      C[row + tn + c] = v;
    }
  }
}

// ---------------------------------------------------------------- bf16 MFMA GEMM
// C[M,N] fp32 = A_bf[M,K] @ (BT ? B_bf[N,K]^T : B_bf[K,N]) (+bias)
// tile 128x128, BK=32, 256 threads = 4 waves (each 64x64 quadrant, 4x4 frags of 16x16x32).
// M%128==0, K%32==0 required; N guarded (score GEMM: N=40000 = 312*128 + 64).
template <int BT, int BIAS>
__global__ __launch_bounds__(256) void mfma_gemm(const ushort* __restrict__ A,
    const ushort* __restrict__ B, const float* __restrict__ bias,
    float* __restrict__ C, int M, int N, int K) {
  __shared__ ushort Asm[128][40];   // [m][k], +8 pad: row stride 80B (16B-aligned)
  __shared__ ushort Bsm[128][40];   // [n][k]
  int tid = threadIdx.x;
  int bm = blockIdx.y * 128, bn = blockIdx.x * 128;
  int lane = tid & 63, wave = tid >> 6;
  int quad = lane >> 4, l16 = lane & 15;
  int wm = (wave >> 1) * 64, wn = (wave & 1) * 64;
  f32x4 acc[4][4] = {};
  for (int k0 = 0; k0 < K; k0 += 32) {
#pragma unroll
    for (int u = 0; u < 2; ++u) {               // A: 128x32, 16B per thread x2
      int idx = tid + u * 256;
      int r = idx >> 2, kc = (idx & 3) * 8;
      uint4 v = *(const uint4*)(A + (size_t)(bm + r) * K + k0 + kc);
      *(uint4*)&Asm[r][kc] = v;
    }
    if (BT) {
#pragma unroll
      for (int u = 0; u < 2; ++u) {
        int idx = tid + u * 256;
        int r = idx >> 2, kc = (idx & 3) * 8;
        uint4 v = make_uint4(0u, 0u, 0u, 0u);
        if (bn + r < N) v = *(const uint4*)(B + (size_t)(bn + r) * K + k0 + kc);
        *(uint4*)&Bsm[r][kc] = v;
      }
    } else {
#pragma unroll
      for (int u = 0; u < 8; ++u) {             // transpose-stage: 2 n per thread
        int idx = tid + u * 256;                // 0..2047
        int n2 = (idx & 63) * 2, kk = idx >> 6; // kk 0..31
        uint v = *(const uint*)(B + (size_t)(k0 + kk) * N + bn + n2);
        Bsm[n2][kk] = (ushort)(v & 0xffffu);
        Bsm[n2 + 1][kk] = (ushort)(v >> 16);
      }
    }
    __syncthreads();
    bf16x8 af[4], bfr[4];
#pragma unroll
    for (int f = 0; f < 4; ++f) af[f] = *(const bf16x8*)&Asm[wm + f * 16 + l16][quad * 8];
#pragma unroll
    for (int f = 0; f < 4; ++f) bfr[f] = *(const bf16x8*)&Bsm[wn + f * 16 + l16][quad * 8];
#pragma unroll
    for (int mf = 0; mf < 4; ++mf)
#pragma unroll
      for (int nf = 0; nf < 4; ++nf)
        acc[mf][nf] = __builtin_amdgcn_mfma_f32_16x16x32_bf16(af[mf], bfr[nf], acc[mf][nf], 0, 0, 0);
    __syncthreads();
  }
#pragma unroll
  for (int mf = 0; mf < 4; ++mf) {
#pragma unroll
    for (int r = 0; r < 4; ++r) {
      int row = bm + wm + mf * 16 + quad * 4 + r;
      size_t rowo = (size_t)row * N;
#pragma unroll
      for (int nf = 0; nf < 4; ++nf) {
        int col = bn + wn + nf * 16 + l16;
        if (col < N) {
          float v = acc[mf][nf][r];
          if (BIAS) v += bias[col];
          C[rowo + col] = v;
        }
      }
    }
  }
}

// ---------------------------------------------------------------- casts
__global__ void cast_f2b_k(const float* __restrict__ s, ushort* __restrict__ d, int n4) {
  int i = blockIdx.x * 256 + threadIdx.x;
  if (i >= n4) return;
  const float4 v = ((const float4*)s)[i];
  ushort4 o; o.x = f2b(v.x); o.y = f2b(v.y); o.z = f2b(v.z); o.w = f2b(v.w);
  ((ushort4*)d)[i] = o;
}

struct Cast7 { const float* s[7]; ushort* d[7]; };
__global__ void cast7_k(Cast7 p) {
  int m = blockIdx.y;
  int i = blockIdx.x * 256 + threadIdx.x;     // 16384 float4 per 256x256 matrix
  const float4 v = ((const float4*)p.s[m])[i];
  ushort4 o; o.x = f2b(v.x); o.y = f2b(v.y); o.z = f2b(v.z); o.w = f2b(v.w);
  ((ushort4*)p.d[m])[i] = o;
}

// ---------------------------------------------------------------- misc elementwise
__global__ void add_tab0(float* __restrict__ q) {
  int idx = blockIdx.x * 256 + threadIdx.x;
  q[idx] += (float)(threadIdx.x & 1);         // TAB[0]: sin(0)=0, cos(0)=1
}

__global__ void transpose_whh(const float* __restrict__ w, float* __restrict__ wT) {
  int idx = blockIdx.x * 256 + threadIdx.x;   // idx = k*768+r
  int k = idx / 768, r = idx % 768;
  wT[idx] = w[r * 256 + k];
}

__global__ void mask_mul_dual(const float* __restrict__ x, const int* __restrict__ m,
                              float* __restrict__ y, ushort* __restrict__ yb) {
  int idx = blockIdx.x * 256 + threadIdx.x;
  float v = m[idx >> 8] ? x[idx] : 0.0f;
  y[idx] = v;
  yb[idx] = f2b(v);
}

__global__ void add_pe3(float* __restrict__ q, float* __restrict__ k, float* __restrict__ v,
                        const float* __restrict__ TAB, const int* __restrict__ lastp) {
  int idx = blockIdx.x * 256 + threadIdx.x;
  int j = idx & 255, bt = idx >> 8;
  int b = bt / Nsq, t = bt - b * Nsq;
  int d = abs(t - lastp[b]);
  float pe = TAB[d * 256 + j];
  q[idx] += pe; k[idx] += pe; v[idx] += pe;
}

__global__ void relu_add(float* __restrict__ a, const float* __restrict__ b) {
  int idx = blockIdx.x * 256 + threadIdx.x;
  a[idx] = fmaxf(a[idx] + b[idx], 0.0f);
}

// ---------------------------------------------------------------- GRU layer
// 128 blocks x 768 threads; block owns 4 samples for all 50 steps.
// h in LDS (float4 broadcast reads), weights software-prefetched 8 deep.
// Output written as bf16 (optionally masked) — consumer is always a bf16 GEMM.
__global__ __launch_bounds__(768) void gru_layer_kernel(const float* __restrict__ gi,
    const float* __restrict__ whhT, const float* __restrict__ bhh,
    ushort* __restrict__ ysb, const int* __restrict__ mask) {
  __shared__ float h[4][260];       // row stride 1040B (16 | 1040)
  __shared__ float ghs[768][5];
  int tid = threadIdx.x;
  int b0 = blockIdx.x * 4;
  for (int i = tid; i < 1024; i += 768) h[i >> 8][i & 255] = 0.0f;
  float bh = bhh[tid];
  const float* wp = whhT + tid;
  __syncthreads();
  for (int t = 0; t < Nsq; ++t) {
    float a0 = 0.f, a1 = 0.f, a2 = 0.f, a3 = 0.f;
    float wn0[8];
#pragma unroll
    for (int u = 0; u < 8; ++u) wn0[u] = wp[u * 768];
#pragma unroll 2
    for (int k0 = 0; k0 < 256; k0 += 8) {
      float w0[8];
#pragma unroll
      for (int u = 0; u < 8; ++u) w0[u] = wn0[u];
      // prefetch next 8 k (reads past end on last iter land in adjacent ws buffers — safe, unused)
#pragma unroll
      for (int u = 0; u < 8; ++u) wn0[u] = wp[(k0 + 8 + u) * 768];
      float4 p0 = *(const float4*)&h[0][k0];
      float4 p1 = *(const float4*)&h[1][k0];
      float4 p2 = *(const float4*)&h[2][k0];
      float4 p3 = *(const float4*)&h[3][k0];
      float4 q0 = *(const float4*)&h[0][k0 + 4];
      float4 q1 = *(const float4*)&h[1][k0 + 4];
      float4 q2 = *(const float4*)&h[2][k0 + 4];
      float4 q3 = *(const float4*)&h[3][k0 + 4];
      a0 += w0[0]*p0.x + w0[1]*p0.y + w0[2]*p0.z + w0[3]*p0.w
          + w0[4]*q0.x + w0[5]*q0.y + w0[6]*q0.z + w0[7]*q0.w;
      a1 += w0[0]*p1.x + w0[1]*p1.y + w0[2]*p1.z + w0[3]*p1.w
          + w0[4]*q1.x + w0[5]*q1.y + w0[6]*q1.z + w0[7]*q1.w;
      a2 += w0[0]*p2.x + w0[1]*p2.y + w0[2]*p2.z + w0[3]*p2.w
          + w0[4]*q2.x + w0[5]*q2.y + w0[6]*q2.z + w0[7]*q2.w;
      a3 += w0[0]*p3.x + w0[1]*p3.y + w0[2]*p3.z + w0[3]*p3.w
          + w0[4]*q3.x + w0[5]*q3.y + w0[6]*q3.z + w0[7]*q3.w;
    }
    ghs[tid][0] = a0 + bh; ghs[tid][1] = a1 + bh; ghs[tid][2] = a2 + bh; ghs[tid][3] = a3 + bh;
    __syncthreads();
    for (int idx = tid; idx < 1024; idx += 768) {
      int r = idx >> 8, jj = idx & 255;
      int bb = b0 + r;
      const float* gib = gi + ((size_t)bb * Nsq + t) * 768;
      float ir = gib[jj], iz = gib[256 + jj], inn = gib[512 + jj];
      float hr = ghs[jj][r], hz = ghs[256 + jj][r], hn = ghs[512 + jj][r];
      float rr = sigmoidf_(ir + hr);
      float zz = sigmoidf_(iz + hz);
      float nn = tanh_fast(inn + rr * hn);
      float h2 = (1.0f - zz) * nn + zz * h[r][jj];
      h[r][jj] = h2;
      float ov = h2;
      if (mask) ov = mask[bb * Nsq + t] ? h2 : 0.0f;
      ysb[((size_t)bb * Nsq + t) * 256 + jj] = f2b(ov);
    }
    __syncthreads();
  }
}

// ---------------------------------------------------------------- attention 1 (causal self)
__global__ __launch_bounds__(256) void attn1_kernel(const float* __restrict__ q1,
    const float* __restrict__ k1, const float* __restrict__ v1,
    const int* __restrict__ mask, ushort* __restrict__ out) {
  int b = blockIdx.x, tid = threadIdx.x;
  __shared__ float Ks[50][257];
  __shared__ float qs[256];
  __shared__ float ps[64];
  __shared__ float part[64][5];
  __shared__ int msk[50];
  const float* kb = k1 + (size_t)b * Nsq * Hd;
  for (int i = tid; i < 50 * 256; i += 256) Ks[i >> 8][i & 255] = kb[i];
  if (tid < 50) msk[tid] = mask[b * Nsq + tid];
  __syncthreads();
  const float* vb = v1 + (size_t)b * Nsq * Hd;
  for (int t = 0; t < Nsq; ++t) {
    qs[tid] = q1[((size_t)b * Nsq + t) * Hd + tid];
    __syncthreads();
    int j = tid & 63, w = tid >> 6;
    float p = 0.0f;
    if (j < 50) {
      const float* kr = &Ks[j][w * 64];
      const float* qr = &qs[w * 64];
#pragma unroll
      for (int hh = 0; hh < 64; ++hh) p += qr[hh] * kr[hh];
    }
    part[j][w] = p;
    __syncthreads();
    if (tid < 64) {
      float s = part[tid][0] + part[tid][1] + part[tid][2] + part[tid][3];
      bool ok = (tid < 50) && (tid <= t) && (msk[tid] != 0);
      s = ok ? s * SCALE_C : NEG_C;
      float m = s;
      for (int off = 32; off; off >>= 1) m = fmaxf(m, __shfl_xor(m, off));
      float e = expf(s - m);
      float sum = e;
      for (int off = 32; off; off >>= 1) sum += __shfl_xor(sum, off);
      ps[tid] = e / sum;
    }
    __syncthreads();
    float o = 0.0f;
    for (int jj = 0; jj <= t; ++jj) o += ps[jj] * vb[jj * 256 + tid];
    if (!msk[t]) o = 0.0f;
    out[((size_t)b * Nsq + t) * Hd + tid] = f2b(o);
    __syncthreads();
  }
}

// ---------------------------------------------------------------- attention 2 (mem + causal)
__global__ __launch_bounds__(256) void attn2_kernel(const float* __restrict__ q1,
    const float* __restrict__ k2, const float* __restrict__ v2,
    const float* __restrict__ memk, const float* __restrict__ memv,
    const int* __restrict__ mask, ushort* __restrict__ out) {
  int b = blockIdx.x, tid = threadIdx.x;
  __shared__ float Ks[58][257];
  __shared__ float qs[256];
  __shared__ float ps[64];
  __shared__ float part[64][5];
  __shared__ int msk[50];
  for (int i = tid; i < 58 * 256; i += 256) {
    int row = i >> 8, col = i & 255;
    Ks[row][col] = (row < 8) ? memk[row * 256 + col]
                             : k2[((size_t)b * Nsq + (row - 8)) * 256 + col];
  }
  if (tid < 50) msk[tid] = mask[b * Nsq + tid];
  __syncthreads();
  for (int t = 0; t < Nsq; ++t) {
    qs[tid] = q1[((size_t)b * Nsq + t) * Hd + tid];
    __syncthreads();
    int j = tid & 63, w = tid >> 6;
    float p = 0.0f;
    if (j < 58) {
      const float* kr = &Ks[j][w * 64];
      const float* qr = &qs[w * 64];
#pragma unroll
      for (int hh = 0; hh < 64; ++hh) p += qr[hh] * kr[hh];
    }
    part[j][w] = p;
    __syncthreads();
    if (tid < 64) {
      float s = part[tid][0] + part[tid][1] + part[tid][2] + part[tid][3];
      bool ok;
      if (tid < 8) ok = true;
      else if (tid < 58) ok = ((tid - 8) <= t) && (msk[tid - 8] != 0);
      else ok = false;
      s = ok ? s * SCALE_C : NEG_C;
      float m = s;
      for (int off = 32; off; off >>= 1) m = fmaxf(m, __shfl_xor(m, off));
      float e = expf(s - m);
      float sum = e;
      for (int off = 32; off; off >>= 1) sum += __shfl_xor(sum, off);
      ps[tid] = e / sum;
    }
    __syncthreads();
    float o = 0.0f;
    int jmax = min(57, t + 8);
    for (int jj = 0; jj <= jmax; ++jj) {
      float vv = (jj < 8) ? memv[jj * 256 + tid]
                          : v2[((size_t)b * Nsq + (jj - 8)) * 256 + tid];
      o += ps[jj] * vv;
    }
    if (!msk[t]) o = 0.0f;
    out[((size_t)b * Nsq + t) * Hd + tid] = f2b(o);
    __syncthreads();
  }
}

// ---------------------------------------------------------------- alpha + sess (→ sesscat)
__global__ __launch_bounds__(256) void alpha_sess_kernel(const float* __restrict__ att,
    const float* __restrict__ W3, const float* __restrict__ q11,
    const float* __restrict__ se1, const int* __restrict__ mask,
    const float* __restrict__ srl, float* __restrict__ sesscat) {
  int b = blockIdx.x, tid = threadIdx.x;
  __shared__ float red[256];
  __shared__ float ash[50];
  red[tid] = q11[b * Hd + tid] * W3[256 + tid];
  __syncthreads();
  for (int s = 128; s; s >>= 1) { if (tid < s) red[tid] += red[tid + s]; __syncthreads(); }
  float cq = red[0];
  float aval = 0.0f;
  if (tid < 50) {
    float s = cq;
    const float* ar = att + ((size_t)b * Nsq + tid) * Hd;
    for (int hh = 0; hh < 256; ++hh) s += ar[hh] * W3[hh];
    aval = mask[b * Nsq + tid] ? s : NEG_C;
  }
  if (tid < 64) {
    float s = (tid < 50) ? aval : NEG_C;
    float m = s;
    for (int off = 32; off; off >>= 1) m = fmaxf(m, __shfl_xor(m, off));
    float e = expf(s - m);
    float sum = e;
    for (int off = 32; off; off >>= 1) sum += __shfl_xor(sum, off);
    if (tid < 50) ash[tid] = e / sum;
  }
  __syncthreads();
  float acc = 0.0f;
  const float* se = se1 + (size_t)b * Nsq * Hd;
  for (int t = 0; t < Nsq; ++t) acc += ash[t] * se[t * 256 + tid];
  sesscat[(size_t)b * 512 + tid] = acc;
  sesscat[(size_t)b * 512 + 256 + tid] = srl[b * Hd + tid];
}

// ---------------------------------------------------------------- beta + boundary (fp32)
__global__ __launch_bounds__(256) void beta_kernel(const float* __restrict__ sess2,
    const float* __restrict__ Wt1, const float* __restrict__ bt1,
    const float* __restrict__ Wt2, float* __restrict__ beta, float* __restrict__ bnd) {
  int b = blockIdx.x, tid = threadIdx.x;
  __shared__ float xs[256];
  __shared__ float r0[256], r1[256];
  xs[tid] = sess2[b * Hd + tid];
  __syncthreads();
  float hsum = bt1[tid];
  for (int k = 0; k < 256; ++k) hsum += xs[k] * Wt1[k * 256 + tid];
  float hid = fmaxf(hsum, 0.0f);
  r0[tid] = hid * Wt2[tid * 2 + 0];
  r1[tid] = hid * Wt2[tid * 2 + 1];
  __syncthreads();
  for (int s = 128; s; s >>= 1) {
    if (tid < s) { r0[tid] += r0[tid + s]; r1[tid] += r1[tid + s]; }
    __syncthreads();
  }
  if (tid == 0) {
    float t0 = r0[0], t1 = r1[0];
    float m = fmaxf(t0, t1);
    float e0 = expf(t0 - m), e1 = expf(t1 - m);
    float bb0 = e0 / (e0 + e1), bb1 = e1 / (e0 + e1);
    beta[b * 2] = bb0; beta[b * 2 + 1] = bb1;
    atomicAdd(bnd, fabsf(bb0 - bb1) * (1.0f / 512.0f));
  }
}

// ---------------------------------------------------------------- score softmax stats
__global__ __launch_bounds__(256) void score_stats_kernel(const float* __restrict__ score,
    const int* __restrict__ flag, float* __restrict__ stats) {
  int b = blockIdx.x, tid = threadIdx.x;
  float mi = -INFINITY, si = 0.0f, me = -INFINITY, se = 0.0f;
  const float* sr = score + (size_t)b * VM1;
  const int* fr = flag + (size_t)b * VM1;
  for (int i = tid; i < VM1; i += 256) {
    float s = sr[i];
    int f = fr[i];
    float vi = f ? s : NEG_C;
    float ve = f ? NEG_C : s;
    float mni = fmaxf(mi, vi); si = si * expf(mi - mni) + expf(vi - mni); mi = mni;
    float mne = fmaxf(me, ve); se = se * expf(me - mne) + expf(ve - mne); me = mne;
  }
  __shared__ float red[256];
  red[tid] = mi; __syncthreads();
  for (int s = 128; s; s >>= 1) { if (tid < s) red[tid] = fmaxf(red[tid], red[tid + s]); __syncthreads(); }
  float Mi = red[0]; __syncthreads();
  red[tid] = si * expf(mi - Mi); __syncthreads();
  for (int s = 128; s; s >>= 1) { if (tid < s) red[tid] += red[tid + s]; __syncthreads(); }
  float Si = red[0]; __syncthreads();
  red[tid] = me; __syncthreads();
  for (int s = 128; s; s >>= 1) { if (tid < s) red[tid] = fmaxf(red[tid], red[tid + s]); __syncthreads(); }
  float Me = red[0]; __syncthreads();
  red[tid] = se * expf(me - Me); __syncthreads();
  for (int s = 128; s; s >>= 1) { if (tid < s) red[tid] += red[tid + s]; __syncthreads(); }
  float Se = red[0];
  if (tid == 0) { stats[b * 4] = Mi; stats[b * 4 + 1] = Si; stats[b * 4 + 2] = Me; stats[b * 4 + 3] = Se; }
}

// ---------------------------------------------------------------- final (in-place on score)
__global__ void final_kernel(float* __restrict__ score, const int* __restrict__ flag,
                             const float* __restrict__ stats, const float* __restrict__ beta) {
  int idx = blockIdx.x * 256 + threadIdx.x;
  int b = idx / VM1;
  float s = score[idx];
  int f = flag[idx];
  float vi = f ? s : NEG_C;
  float ve = f ? NEG_C : s;
  float fin = beta[b * 2] * expf(vi - stats[b * 4]) / stats[b * 4 + 1]
            + beta[b * 2 + 1] * expf(ve - stats[b * 4 + 2]) / stats[b * 4 + 3];
  score[idx] = fin;
}

// ================================================================ launch
extern "C" void kernel_launch(void* const* d_in, const int* in_sizes, int n_in,
                              void* d_out, int out_size, void* d_ws, size_t ws_size,
                              hipStream_t stream) {
  const float* seq1  = (const float*)d_in[0];
  const float* seq2  = (const float*)d_in[1];
  const int*   mask  = (const int*)d_in[2];
  const int*   iflag = (const int*)d_in[3];
  const float* wih0  = (const float*)d_in[4];
  const float* whh0  = (const float*)d_in[5];
  const float* bih0  = (const float*)d_in[6];
  const float* bhh0  = (const float*)d_in[7];
  const float* wih1  = (const float*)d_in[8];
  const float* whh1  = (const float*)d_in[9];
  const float* bih1  = (const float*)d_in[10];
  const float* bhh1  = (const float*)d_in[11];
  const float* Wq1   = (const float*)d_in[12];
  const float* Wk1   = (const float*)d_in[13];
  const float* Wv1   = (const float*)d_in[14];
  const float* Wk2   = (const float*)d_in[16];
  const float* Wv2   = (const float*)d_in[17];
  const float* Wffn1 = (const float*)d_in[18];
  const float* bffn1 = (const float*)d_in[19];
  const float* Wffn2 = (const float*)d_in[20];
  const float* bffn2 = (const float*)d_in[21];
  const float* Wone  = (const float*)d_in[22];
  const float* bone  = (const float*)d_in[23];
  const float* W3    = (const float*)d_in[24];
  const float* Wtr   = (const float*)d_in[25];
  const float* btr   = (const float*)d_in[26];
  const float* Wt1   = (const float*)d_in[27];
  const float* bt1   = (const float*)d_in[28];
  const float* Wt2   = (const float*)d_in[29];
  const float* memk  = (const float*)d_in[30];
  const float* memv  = (const float*)d_in[31];
  const float* emb1  = (const float*)d_in[32];
  float* out = (float*)d_out;

  // Workspace layout (byte offsets, all 16B-aligned). Total ≈ 214.1 MB.
  char* wsb = (char*)d_ws;
  float*  TAB    = (float*)(wsb + 0);            // 51,200
  int*    lastp  = (int*)  (wsb + 51200);        // 2,048
  float*  srl    = (float*)(wsb + 53248);        // 524,288
  float*  q11    = (float*)(wsb + 577536);       // 524,288
  float*  whhT0  = (float*)(wsb + 1101824);      // 786,432
  float*  whhT1  = (float*)(wsb + 1888256);      // 786,432
  ushort* wih0b  = (ushort*)(wsb + 2674688);     // 393,216
  ushort* wih1b  = (ushort*)(wsb + 3067904);     // 393,216
  ushort* w7b    = (ushort*)(wsb + 3461120);     // 7 x 131,072
  ushort* bufS   = (ushort*)(wsb + 4378624);     // 13,107,200  seq2b -> ys1b -> se2b
  float*  se1    = (float*)(wsb + 17485824);     // 26,214,400
  ushort* se1b   = (ushort*)(wsb + 43700224);    // 13,107,200
  float*  giQ    = (float*)(wsb + 56807424);     // 78,643,200  gi -> q1|k1|v1 -> tail
  float*  kv2a   = (float*)(wsb + 135450624);    // 26,214,400  k2 -> att1p
  float*  kv2b   = (float*)(wsb + 161665024);    // 26,214,400  v2 -> att2p
  ushort* ao1b   = (ushort*)(wsb + 187879424);   // 13,107,200
  ushort* ao2b   = (ushort*)(wsb + 200986624);   // 13,107,200

  float* gi = giQ;
  float* q1 = giQ;
  float* k1 = giQ + 6553600;
  float* v1 = giQ + 13107200;
  // tail block (reuses giQ after attn2):
  ushort* embB    = (ushort*)giQ;                             // 20,480,000 B
  float*  sesscat = (float*)((char*)giQ + 20480000);          // 1,048,576
  float*  sess2   = (float*)((char*)giQ + 21528576);          // 524,288
  ushort* sess2b  = (ushort*)((char*)giQ + 22052864);         // 262,144
  float*  betab   = (float*)((char*)giQ + 22315008);          // 4,096
  float*  stats   = (float*)((char*)giQ + 22319104);          // 8,192
  float*  bnd     = out + (size_t)Bsz * VM1;                  // boundary output slot

  ushort* Wq1b = w7b;              ushort* Wk1b = w7b + 65536;
  ushort* Wv1b = w7b + 131072;     ushort* Wk2b = w7b + 196608;
  ushort* Wv2b = w7b + 262144;     ushort* Wf1b = w7b + 327680;
  ushort* Wf2b = w7b + 393216;

  // ---- table / last / q1_1 (fp32 path)
  build_tab<<<50, 256, 0, stream>>>(TAB);
  last_srl_kernel<<<Bsz, 256, 0, stream>>>(mask, seq1, lastp, srl);
  gemm_tile<0, 1><<<dim3(4, 4), 256, 0, stream>>>(srl, Wone, bone, q11, 512, 256, 256);
  add_tab0<<<512, 256, 0, stream>>>(q11);

  // ---- weight casts / transposes
  cast_f2b_k<<<6400, 256, 0, stream>>>(seq2, bufS, 1638400);
  cast_f2b_k<<<192, 256, 0, stream>>>(wih0, wih0b, 49152);
  cast_f2b_k<<<192, 256, 0, stream>>>(wih1, wih1b, 49152);
  Cast7 c7;
  c7.s[0] = Wq1; c7.s[1] = Wk1; c7.s[2] = Wv1; c7.s[3] = Wk2; c7.s[4] = Wv2;
  c7.s[5] = Wffn1; c7.s[6] = Wffn2;
  c7.d[0] = Wq1b; c7.d[1] = Wk1b; c7.d[2] = Wv1b; c7.d[3] = Wk2b; c7.d[4] = Wv2b;
  c7.d[5] = Wf1b; c7.d[6] = Wf2b;
  cast7_k<<<dim3(64, 7), 256, 0, stream>>>(c7);
  transpose_whh<<<768, 256, 0, stream>>>(whh0, whhT0);
  transpose_whh<<<768, 256, 0, stream>>>(whh1, whhT1);

  // ---- GRU (gi via MFMA, recurrence fp32)
  mfma_gemm<1, 1><<<dim3(6, 200), 256, 0, stream>>>(bufS, wih0b, bih0, gi, 25600, 768, 256);
  gru_layer_kernel<<<128, 768, 0, stream>>>(gi, whhT0, bhh0, bufS, nullptr);
  mfma_gemm<1, 1><<<dim3(6, 200), 256, 0, stream>>>(bufS, wih1b, bih1, gi, 25600, 768, 256);
  gru_layer_kernel<<<128, 768, 0, stream>>>(gi, whhT1, bhh1, bufS, mask);   // -> se2 bf16

  // ---- masked seq1 (fp32 + bf16)
  mask_mul_dual<<<25600, 256, 0, stream>>>(seq1, mask, se1, se1b);

  // ---- projections (MFMA)
  mfma_gemm<0, 0><<<dim3(2, 200), 256, 0, stream>>>(bufS, Wk2b, nullptr, kv2a, 25600, 256, 256);
  mfma_gemm<0, 0><<<dim3(2, 200), 256, 0, stream>>>(bufS, Wv2b, nullptr, kv2b, 25600, 256, 256);
  mfma_gemm<0, 0><<<dim3(2, 200), 256, 0, stream>>>(se1b, Wq1b, nullptr, q1, 25600, 256, 256);
  mfma_gemm<0, 0><<<dim3(2, 200), 256, 0, stream>>>(se1b, Wk1b, nullptr, k1, 25600, 256, 256);
  mfma_gemm<0, 0><<<dim3(2, 200), 256, 0, stream>>>(se1b, Wv1b, nullptr, v1, 25600, 256, 256);
  add_pe3<<<25600, 256, 0, stream>>>(q1, k1, v1, TAB, lastp);

  // ---- attentions (fp32 in, bf16 out)
  attn1_kernel<<<Bsz, 256, 0, stream>>>(q1, k1, v1, mask, ao1b);
  attn2_kernel<<<Bsz, 256, 0, stream>>>(q1, kv2a, kv2b, memk, memv, mask, ao2b);
  mfma_gemm<0, 1><<<dim3(2, 200), 256, 0, stream>>>(ao1b, Wf1b, bffn1, kv2a, 25600, 256, 256);
  mfma_gemm<0, 1><<<dim3(2, 200), 256, 0, stream>>>(ao2b, Wf2b, bffn2, kv2b, 25600, 256, 256);
  relu_add<<<25600, 256, 0, stream>>>(kv2a, kv2b);          // att

  // ---- pooling + session (fp32)
  alpha_sess_kernel<<<Bsz, 256, 0, stream>>>(kv2a, W3, q11, se1, mask, srl, sesscat);
  gemm_tile<0, 1><<<dim3(4, 4), 256, 0, stream>>>(sesscat, Wtr, btr, sess2, 512, 256, 512);
  cast_f2b_k<<<128, 256, 0, stream>>>(sess2, sess2b, 32768);

  // ---- tail gating (fp32) + scoring (MFMA)
  hipMemsetAsync(bnd, 0, 4, stream);
  beta_kernel<<<Bsz, 256, 0, stream>>>(sess2, Wt1, bt1, Wt2, betab, bnd);
  cast_f2b_k<<<10000, 256, 0, stream>>>(emb1 + 256, embB, 2560000);
  mfma_gemm<1, 0><<<dim3(313, 4), 256, 0, stream>>>(sess2b, embB, nullptr, out, 512, VM1, 256);
  score_stats_kernel<<<Bsz, 256, 0, stream>>>(out, iflag, stats);
  final_kernel<<<80000, 256, 0, stream>>>(out, iflag, stats, betab);

  (void)in_sizes; (void)n_in; (void)out_size; (void)ws_size;
}

// Round 3
// 1410.126 us; speedup vs baseline: 2.1112x; 1.6726x over previous
//
#include <hip/hip_runtime.h>
#include <hip/hip_bf16.h>
#include <cstdint>
#include <cstddef>

// Problem dims
#define Bsz 512
#define Nsq 50
#define Hd  256
#define VM1 40000
static constexpr float SCALE_C = 0.0625f;   // 1/sqrt(256)
static constexpr float NEG_C   = -1.0e12f;

typedef __attribute__((ext_vector_type(8))) short bf16x8;
typedef __attribute__((ext_vector_type(4))) float f32x4;

__device__ __forceinline__ float sigmoidf_(float x) { return 1.0f / (1.0f + __expf(-x)); }
__device__ __forceinline__ float tanh_fast(float x) {
  float t = fminf(fmaxf(2.0f * x, -60.0f), 60.0f);
  float e = __expf(t);
  return (e - 1.0f) / (e + 1.0f);
}
__device__ __forceinline__ ushort f2b(float x) {   // fp32 -> bf16 (RNE)
  union { float f; uint32_t u; } c; c.f = x;
  uint32_t r = (c.u + 0x7fffu + ((c.u >> 16) & 1u)) >> 16;
  return (ushort)r;
}

// ---------------------------------------------------------------- TAB (50x256)
__global__ void build_tab(float* __restrict__ TAB) {
  int idx = blockIdx.x * 256 + threadIdx.x;
  int pos = idx >> 8, j = idx & 255;
  int pair = j >> 1;
  float expo = (2.0f * (float)pair) / 256.0f;
  float inv = powf(10000.0f, -expo);
  float ang = (float)pos * inv;
  TAB[idx] = (j & 1) ? cosf(ang) : sinf(ang);
}

// ------------------------------------------------- last[b], sr_l_1 = seq1[b,last]
__global__ __launch_bounds__(256) void last_srl_kernel(const int* __restrict__ mask,
    const float* __restrict__ seq1, int* __restrict__ lastp, float* __restrict__ srl) {
  int b = blockIdx.x, tid = threadIdx.x;
  __shared__ int ls;
  if (tid == 0) {
    int c = 0;
    for (int t = 0; t < Nsq; ++t) c += mask[b * Nsq + t];
    ls = c - 1;
    lastp[b] = c - 1;
  }
  __syncthreads();
  srl[b * Hd + tid] = seq1[((size_t)b * Nsq + ls) * Hd + tid];
}

// ---------------------------------------------------------------- fp32 GEMM (small shapes only)
template <int BT, int BIAS>
__global__ __launch_bounds__(256) void gemm_tile(const float* __restrict__ A,
    const float* __restrict__ B, const float* __restrict__ bias,
    float* __restrict__ C, int M, int N, int K) {
  __shared__ float As[16][132];
  __shared__ float Bs[16][68];
  int bm = blockIdx.y * 128, bn = blockIdx.x * 64;
  int tid = threadIdx.x;
  int tm = (tid >> 4) << 3;
  int tn = (tid & 15) << 2;
  float acc[8][4] = {};
  for (int k0 = 0; k0 < K; k0 += 16) {
#pragma unroll
    for (int u = 0; u < 8; ++u) {
      int i = tid + u * 256;
      int kk = i & 15, m = i >> 4;
      As[kk][m] = A[(size_t)(bm + m) * K + (k0 + kk)];
    }
#pragma unroll
    for (int u = 0; u < 4; ++u) {
      int i = tid + u * 256;
      if (BT) {
        int kk = i & 15, n = i >> 4;
        Bs[kk][n] = B[(size_t)(bn + n) * K + (k0 + kk)];
      } else {
        int n = i & 63, kk = i >> 6;
        Bs[kk][n] = B[(size_t)(k0 + kk) * N + (bn + n)];
      }
    }
    __syncthreads();
#pragma unroll
    for (int kk = 0; kk < 16; ++kk) {
      float a[8], bb[4];
#pragma unroll
      for (int r = 0; r < 8; ++r) a[r] = As[kk][tm + r];
#pragma unroll
      for (int c = 0; c < 4; ++c) bb[c] = Bs[kk][tn + c];
#pragma unroll
      for (int r = 0; r < 8; ++r)
#pragma unroll
        for (int c = 0; c < 4; ++c) acc[r][c] += a[r] * bb[c];
    }
    __syncthreads();
  }
#pragma unroll
  for (int r = 0; r < 8; ++r) {
    size_t row = (size_t)(bm + tm + r) * N + bn;
#pragma unroll
    for (int c = 0; c < 4; ++c) {
      float v = acc[r][c];
      if (BIAS) v += bias[bn + tn + c];
      C[row + tn + c] = v;
    }
  }
}

// ---------------------------------------------------------------- bf16 MFMA GEMM
// C[M,N] fp32 = A_bf[M,K] @ (BT ? B_bf[N,K]^T : B_bf[K,N]) (+bias)
// tile 128x128, BK=32, 256 threads = 4 waves (each 64x64 quadrant, 4x4 frags of 16x16x32).
template <int BT, int BIAS>
__global__ __launch_bounds__(256) void mfma_gemm(const ushort* __restrict__ A,
    const ushort* __restrict__ B, const float* __restrict__ bias,
    float* __restrict__ C, int M, int N, int K) {
  __shared__ ushort Asm[128][40];   // [m][k], +8 pad
  __shared__ ushort Bsm[128][40];   // [n][k]
  int tid = threadIdx.x;
  int bm = blockIdx.y * 128, bn = blockIdx.x * 128;
  int lane = tid & 63, wave = tid >> 6;
  int quad = lane >> 4, l16 = lane & 15;
  int wm = (wave >> 1) * 64, wn = (wave & 1) * 64;
  f32x4 acc[4][4] = {};
  for (int k0 = 0; k0 < K; k0 += 32) {
#pragma unroll
    for (int u = 0; u < 2; ++u) {               // A: 128x32, 16B per thread x2
      int idx = tid + u * 256;
      int r = idx >> 2, kc = (idx & 3) * 8;
      uint4 v = *(const uint4*)(A + (size_t)(bm + r) * K + k0 + kc);
      *(uint4*)&Asm[r][kc] = v;
    }
    if (BT) {
#pragma unroll
      for (int u = 0; u < 2; ++u) {
        int idx = tid + u * 256;
        int r = idx >> 2, kc = (idx & 3) * 8;
        uint4 v = make_uint4(0u, 0u, 0u, 0u);
        if (bn + r < N) v = *(const uint4*)(B + (size_t)(bn + r) * K + k0 + kc);
        *(uint4*)&Bsm[r][kc] = v;
      }
    } else {
#pragma unroll
      for (int u = 0; u < 8; ++u) {             // transpose-stage: 2 n per thread
        int idx = tid + u * 256;
        int n2 = (idx & 63) * 2, kk = idx >> 6;
        uint v = *(const uint*)(B + (size_t)(k0 + kk) * N + bn + n2);
        Bsm[n2][kk] = (ushort)(v & 0xffffu);
        Bsm[n2 + 1][kk] = (ushort)(v >> 16);
      }
    }
    __syncthreads();
    bf16x8 af[4], bfr[4];
#pragma unroll
    for (int f = 0; f < 4; ++f) af[f] = *(const bf16x8*)&Asm[wm + f * 16 + l16][quad * 8];
#pragma unroll
    for (int f = 0; f < 4; ++f) bfr[f] = *(const bf16x8*)&Bsm[wn + f * 16 + l16][quad * 8];
#pragma unroll
    for (int mf = 0; mf < 4; ++mf)
#pragma unroll
      for (int nf = 0; nf < 4; ++nf)
        acc[mf][nf] = __builtin_amdgcn_mfma_f32_16x16x32_bf16(af[mf], bfr[nf], acc[mf][nf], 0, 0, 0);
    __syncthreads();
  }
#pragma unroll
  for (int mf = 0; mf < 4; ++mf) {
#pragma unroll
    for (int r = 0; r < 4; ++r) {
      int row = bm + wm + mf * 16 + quad * 4 + r;
      size_t rowo = (size_t)row * N;
#pragma unroll
      for (int nf = 0; nf < 4; ++nf) {
        int col = bn + wn + nf * 16 + l16;
        if (col < N) {
          float v = acc[mf][nf][r];
          if (BIAS) v += bias[col];
          C[rowo + col] = v;
        }
      }
    }
  }
}

// ---------------------------------------------------------------- casts
__global__ void cast_f2b_k(const float* __restrict__ s, ushort* __restrict__ d, int n4) {
  int i = blockIdx.x * 256 + threadIdx.x;
  if (i >= n4) return;
  const float4 v = ((const float4*)s)[i];
  ushort4 o; o.x = f2b(v.x); o.y = f2b(v.y); o.z = f2b(v.z); o.w = f2b(v.w);
  ((ushort4*)d)[i] = o;
}

struct Cast7 { const float* s[7]; ushort* d[7]; };
__global__ void cast7_k(Cast7 p) {
  int m = blockIdx.y;
  int i = blockIdx.x * 256 + threadIdx.x;
  const float4 v = ((const float4*)p.s[m])[i];
  ushort4 o; o.x = f2b(v.x); o.y = f2b(v.y); o.z = f2b(v.z); o.w = f2b(v.w);
  ((ushort4*)p.d[m])[i] = o;
}

// ---------------------------------------------------------------- misc elementwise
__global__ void add_tab0(float* __restrict__ q) {
  int idx = blockIdx.x * 256 + threadIdx.x;
  q[idx] += (float)(threadIdx.x & 1);         // TAB[0]: sin(0)=0, cos(0)=1
}

__global__ void mask_mul_dual(const float* __restrict__ x, const int* __restrict__ m,
                              float* __restrict__ y, ushort* __restrict__ yb) {
  int idx = blockIdx.x * 256 + threadIdx.x;
  float v = m[idx >> 8] ? x[idx] : 0.0f;
  y[idx] = v;
  yb[idx] = f2b(v);
}

__global__ void add_pe3(float* __restrict__ q, float* __restrict__ k, float* __restrict__ v,
                        const float* __restrict__ TAB, const int* __restrict__ lastp) {
  int idx = blockIdx.x * 256 + threadIdx.x;
  int j = idx & 255, bt = idx >> 8;
  int b = bt / Nsq, t = bt - b * Nsq;
  int d = abs(t - lastp[b]);
  float pe = TAB[d * 256 + j];
  q[idx] += pe; k[idx] += pe; v[idx] += pe;
}

__global__ void relu_add(float* __restrict__ a, const float* __restrict__ b) {
  int idx = blockIdx.x * 256 + threadIdx.x;
  a[idx] = fmaxf(a[idx] + b[idx], 0.0f);
}

// ---------------------------------------------------------------- GRU layer (MFMA, reg-resident weights)
// 256 blocks x 256 threads (4 waves, 1 wave/SIMD). Block owns samples {2b, 2b+1}.
// Wave w holds whh rows [w*192, w*192+192) x k256 as 96 bf16x8 register fragments,
// loaded ONCE, reused for all 50 timesteps. Per step: gh = h @ whh^T via 96 MFMAs/wave
// (A tile: samples in rows 0-1, rest zero), then fp32 gate update.
__global__ __launch_bounds__(256, 1) void gru_mfma_kernel(const float* __restrict__ gi,
    const ushort* __restrict__ whhb, const float* __restrict__ bhh,
    ushort* __restrict__ ysb, const int* __restrict__ mask) {
  __shared__ ushort hbf[16][264];   // A-source: [m=sample][k], pad +8 (2-way bank max)
  __shared__ float hs[2][256];      // fp32 h carry
  __shared__ float ghs[768][2];     // gh results [n][sample]
  int tid = threadIdx.x;
  int lane = tid & 63, wave = tid >> 6;
  int q = lane >> 4, l16 = lane & 15;
  int s0 = blockIdx.x * 2;

  for (int i = tid; i < 16 * 264; i += 256) ((ushort*)hbf)[i] = 0;
  hs[0][tid] = 0.0f; hs[1][tid] = 0.0f;

  // ---- weight preload: frag(nf,kf): lane reads whh[n = w*192+nf*16+l16][k = kf*32+q*8 ..+8]
  bf16x8 bw[96];
  const ushort* wbase = whhb + (size_t)(wave * 192 + l16) * 256 + q * 8;
#pragma unroll
  for (int f = 0; f < 96; ++f) {
    int nf = f >> 3, kf = f & 7;
    bw[f] = *(const bf16x8*)(wbase + nf * (16 * 256) + kf * 32);
  }

  float bh0 = bhh[tid], bh1 = bhh[256 + tid], bh2 = bhh[512 + tid];
  const float* gib0 = gi + (size_t)s0 * Nsq * 768;
  const float* gib1 = gi + (size_t)(s0 + 1) * Nsq * 768;
  float g00 = gib0[tid], g01 = gib0[256 + tid], g02 = gib0[512 + tid];
  float g10 = gib1[tid], g11 = gib1[256 + tid], g12 = gib1[512 + tid];
  __syncthreads();

  for (int t = 0; t < Nsq; ++t) {
    // prefetch gi for t+1 (clamped; discarded on last iter)
    int tn = (t + 1 < Nsq) ? t + 1 : t;
    float p00 = gib0[tn * 768 + tid], p01 = gib0[tn * 768 + 256 + tid], p02 = gib0[tn * 768 + 512 + tid];
    float p10 = gib1[tn * 768 + tid], p11 = gib1[tn * 768 + 256 + tid], p12 = gib1[tn * 768 + 512 + tid];

    // ---- MFMA: gh[0:2][w*192 .. +192) ; kf-outer so consecutive MFMAs are independent
    bf16x8 a[8];
#pragma unroll
    for (int kf = 0; kf < 8; ++kf) a[kf] = *(const bf16x8*)&hbf[l16][kf * 32 + q * 8];
    f32x4 acc[12] = {};
#pragma unroll
    for (int kf = 0; kf < 8; ++kf)
#pragma unroll
      for (int nf = 0; nf < 12; ++nf)
        acc[nf] = __builtin_amdgcn_mfma_f32_16x16x32_bf16(a[kf], bw[nf * 8 + kf], acc[nf], 0, 0, 0);
    // extract: C row = quad*4+reg (sample), col = l16 (n). Samples 0,1 -> quad 0, regs 0,1.
    if (q == 0) {
#pragma unroll
      for (int nf = 0; nf < 12; ++nf) {
        int n = wave * 192 + nf * 16 + l16;
        ghs[n][0] = acc[nf][0];
        ghs[n][1] = acc[nf][1];
      }
    }
    __syncthreads();

    // ---- gate update: thread tid handles j=tid for both samples
    {
      float rr = sigmoidf_(g00 + ghs[tid][0] + bh0);
      float zz = sigmoidf_(g01 + ghs[256 + tid][0] + bh1);
      float nn = tanh_fast(g02 + ghs[512 + tid][0] + bh2);
      float h2 = (1.0f - zz) * nn + zz * hs[0][tid];
      hs[0][tid] = h2;
      hbf[0][tid] = f2b(h2);
      float ov = h2;
      if (mask) ov = mask[s0 * Nsq + t] ? h2 : 0.0f;
      ysb[((size_t)s0 * Nsq + t) * 256 + tid] = f2b(ov);
    }
    {
      float rr = sigmoidf_(g10 + ghs[tid][1] + bh0);
      float zz = sigmoidf_(g11 + ghs[256 + tid][1] + bh1);
      float nn = tanh_fast(g12 + ghs[512 + tid][1] + bh2);
      float h2 = (1.0f - zz) * nn + zz * hs[1][tid];
      hs[1][tid] = h2;
      hbf[1][tid] = f2b(h2);
      float ov = h2;
      if (mask) ov = mask[(s0 + 1) * Nsq + t] ? h2 : 0.0f;
      ysb[((size_t)(s0 + 1) * Nsq + t) * 256 + tid] = f2b(ov);
    }
    g00 = p00; g01 = p01; g02 = p02;
    g10 = p10; g11 = p11; g12 = p12;
    __syncthreads();
  }
}

// ---------------------------------------------------------------- attention 1 (causal self)
__global__ __launch_bounds__(256) void attn1_kernel(const float* __restrict__ q1,
    const float* __restrict__ k1, const float* __restrict__ v1,
    const int* __restrict__ mask, ushort* __restrict__ out) {
  int b = blockIdx.x, tid = threadIdx.x;
  __shared__ float Ks[50][257];
  __shared__ float qs[256];
  __shared__ float ps[64];
  __shared__ float part[64][5];
  __shared__ int msk[50];
  const float* kb = k1 + (size_t)b * Nsq * Hd;
  for (int i = tid; i < 50 * 256; i += 256) Ks[i >> 8][i & 255] = kb[i];
  if (tid < 50) msk[tid] = mask[b * Nsq + tid];
  __syncthreads();
  const float* vb = v1 + (size_t)b * Nsq * Hd;
  for (int t = 0; t < Nsq; ++t) {
    qs[tid] = q1[((size_t)b * Nsq + t) * Hd + tid];
    __syncthreads();
    int j = tid & 63, w = tid >> 6;
    float p = 0.0f;
    if (j < 50) {
      const float* kr = &Ks[j][w * 64];
      const float* qr = &qs[w * 64];
#pragma unroll
      for (int hh = 0; hh < 64; ++hh) p += qr[hh] * kr[hh];
    }
    part[j][w] = p;
    __syncthreads();
    if (tid < 64) {
      float s = part[tid][0] + part[tid][1] + part[tid][2] + part[tid][3];
      bool ok = (tid < 50) && (tid <= t) && (msk[tid] != 0);
      s = ok ? s * SCALE_C : NEG_C;
      float m = s;
      for (int off = 32; off; off >>= 1) m = fmaxf(m, __shfl_xor(m, off));
      float e = expf(s - m);
      float sum = e;
      for (int off = 32; off; off >>= 1) sum += __shfl_xor(sum, off);
      ps[tid] = e / sum;
    }
    __syncthreads();
    float o = 0.0f;
    for (int jj = 0; jj <= t; ++jj) o += ps[jj] * vb[jj * 256 + tid];
    if (!msk[t]) o = 0.0f;
    out[((size_t)b * Nsq + t) * Hd + tid] = f2b(o);
    __syncthreads();
  }
}

// ---------------------------------------------------------------- attention 2 (mem + causal)
__global__ __launch_bounds__(256) void attn2_kernel(const float* __restrict__ q1,
    const float* __restrict__ k2, const float* __restrict__ v2,
    const float* __restrict__ memk, const float* __restrict__ memv,
    const int* __restrict__ mask, ushort* __restrict__ out) {
  int b = blockIdx.x, tid = threadIdx.x;
  __shared__ float Ks[58][257];
  __shared__ float qs[256];
  __shared__ float ps[64];
  __shared__ float part[64][5];
  __shared__ int msk[50];
  for (int i = tid; i < 58 * 256; i += 256) {
    int row = i >> 8, col = i & 255;
    Ks[row][col] = (row < 8) ? memk[row * 256 + col]
                             : k2[((size_t)b * Nsq + (row - 8)) * 256 + col];
  }
  if (tid < 50) msk[tid] = mask[b * Nsq + tid];
  __syncthreads();
  for (int t = 0; t < Nsq; ++t) {
    qs[tid] = q1[((size_t)b * Nsq + t) * Hd + tid];
    __syncthreads();
    int j = tid & 63, w = tid >> 6;
    float p = 0.0f;
    if (j < 58) {
      const float* kr = &Ks[j][w * 64];
      const float* qr = &qs[w * 64];
#pragma unroll
      for (int hh = 0; hh < 64; ++hh) p += qr[hh] * kr[hh];
    }
    part[j][w] = p;
    __syncthreads();
    if (tid < 64) {
      float s = part[tid][0] + part[tid][1] + part[tid][2] + part[tid][3];
      bool ok;
      if (tid < 8) ok = true;
      else if (tid < 58) ok = ((tid - 8) <= t) && (msk[tid - 8] != 0);
      else ok = false;
      s = ok ? s * SCALE_C : NEG_C;
      float m = s;
      for (int off = 32; off; off >>= 1) m = fmaxf(m, __shfl_xor(m, off));
      float e = expf(s - m);
      float sum = e;
      for (int off = 32; off; off >>= 1) sum += __shfl_xor(sum, off);
      ps[tid] = e / sum;
    }
    __syncthreads();
    float o = 0.0f;
    int jmax = min(57, t + 8);
    for (int jj = 0; jj <= jmax; ++jj) {
      float vv = (jj < 8) ? memv[jj * 256 + tid]
                          : v2[((size_t)b * Nsq + (jj - 8)) * 256 + tid];
      o += ps[jj] * vv;
    }
    if (!msk[t]) o = 0.0f;
    out[((size_t)b * Nsq + t) * Hd + tid] = f2b(o);
    __syncthreads();
  }
}

// ---------------------------------------------------------------- alpha + sess (→ sesscat)
__global__ __launch_bounds__(256) void alpha_sess_kernel(const float* __restrict__ att,
    const float* __restrict__ W3, const float* __restrict__ q11,
    const float* __restrict__ se1, const int* __restrict__ mask,
    const float* __restrict__ srl, float* __restrict__ sesscat) {
  int b = blockIdx.x, tid = threadIdx.x;
  __shared__ float red[256];
  __shared__ float ash[50];
  red[tid] = q11[b * Hd + tid] * W3[256 + tid];
  __syncthreads();
  for (int s = 128; s; s >>= 1) { if (tid < s) red[tid] += red[tid + s]; __syncthreads(); }
  float cq = red[0];
  float aval = 0.0f;
  if (tid < 50) {
    float s = cq;
    const float* ar = att + ((size_t)b * Nsq + tid) * Hd;
    for (int hh = 0; hh < 256; ++hh) s += ar[hh] * W3[hh];
    aval = mask[b * Nsq + tid] ? s : NEG_C;
  }
  if (tid < 64) {
    float s = (tid < 50) ? aval : NEG_C;
    float m = s;
    for (int off = 32; off; off >>= 1) m = fmaxf(m, __shfl_xor(m, off));
    float e = expf(s - m);
    float sum = e;
    for (int off = 32; off; off >>= 1) sum += __shfl_xor(sum, off);
    if (tid < 50) ash[tid] = e / sum;
  }
  __syncthreads();
  float acc = 0.0f;
  const float* se = se1 + (size_t)b * Nsq * Hd;
  for (int t = 0; t < Nsq; ++t) acc += ash[t] * se[t * 256 + tid];
  sesscat[(size_t)b * 512 + tid] = acc;
  sesscat[(size_t)b * 512 + 256 + tid] = srl[b * Hd + tid];
}

// ---------------------------------------------------------------- beta + boundary (fp32)
__global__ __launch_bounds__(256) void beta_kernel(const float* __restrict__ sess2,
    const float* __restrict__ Wt1, const float* __restrict__ bt1,
    const float* __restrict__ Wt2, float* __restrict__ beta, float* __restrict__ bnd) {
  int b = blockIdx.x, tid = threadIdx.x;
  __shared__ float xs[256];
  __shared__ float r0[256], r1[256];
  xs[tid] = sess2[b * Hd + tid];
  __syncthreads();
  float hsum = bt1[tid];
  for (int k = 0; k < 256; ++k) hsum += xs[k] * Wt1[k * 256 + tid];
  float hid = fmaxf(hsum, 0.0f);
  r0[tid] = hid * Wt2[tid * 2 + 0];
  r1[tid] = hid * Wt2[tid * 2 + 1];
  __syncthreads();
  for (int s = 128; s; s >>= 1) {
    if (tid < s) { r0[tid] += r0[tid + s]; r1[tid] += r1[tid + s]; }
    __syncthreads();
  }
  if (tid == 0) {
    float t0 = r0[0], t1 = r1[0];
    float m = fmaxf(t0, t1);
    float e0 = expf(t0 - m), e1 = expf(t1 - m);
    float bb0 = e0 / (e0 + e1), bb1 = e1 / (e0 + e1);
    beta[b * 2] = bb0; beta[b * 2 + 1] = bb1;
    atomicAdd(bnd, fabsf(bb0 - bb1) * (1.0f / 512.0f));
  }
}

// ---------------------------------------------------------------- score softmax stats
__global__ __launch_bounds__(256) void score_stats_kernel(const float* __restrict__ score,
    const int* __restrict__ flag, float* __restrict__ stats) {
  int b = blockIdx.x, tid = threadIdx.x;
  float mi = -INFINITY, si = 0.0f, me = -INFINITY, se = 0.0f;
  const float* sr = score + (size_t)b * VM1;
  const int* fr = flag + (size_t)b * VM1;
  for (int i = tid; i < VM1; i += 256) {
    float s = sr[i];
    int f = fr[i];
    float vi = f ? s : NEG_C;
    float ve = f ? NEG_C : s;
    float mni = fmaxf(mi, vi); si = si * expf(mi - mni) + expf(vi - mni); mi = mni;
    float mne = fmaxf(me, ve); se = se * expf(me - mne) + expf(ve - mne); me = mne;
  }
  __shared__ float red[256];
  red[tid] = mi; __syncthreads();
  for (int s = 128; s; s >>= 1) { if (tid < s) red[tid] = fmaxf(red[tid], red[tid + s]); __syncthreads(); }
  float Mi = red[0]; __syncthreads();
  red[tid] = si * expf(mi - Mi); __syncthreads();
  for (int s = 128; s; s >>= 1) { if (tid < s) red[tid] += red[tid + s]; __syncthreads(); }
  float Si = red[0]; __syncthreads();
  red[tid] = me; __syncthreads();
  for (int s = 128; s; s >>= 1) { if (tid < s) red[tid] = fmaxf(red[tid], red[tid + s]); __syncthreads(); }
  float Me = red[0]; __syncthreads();
  red[tid] = se * expf(me - Me); __syncthreads();
  for (int s = 128; s; s >>= 1) { if (tid < s) red[tid] += red[tid + s]; __syncthreads(); }
  float Se = red[0];
  if (tid == 0) { stats[b * 4] = Mi; stats[b * 4 + 1] = Si; stats[b * 4 + 2] = Me; stats[b * 4 + 3] = Se; }
}

// ---------------------------------------------------------------- final (in-place on score)
__global__ void final_kernel(float* __restrict__ score, const int* __restrict__ flag,
                             const float* __restrict__ stats, const float* __restrict__ beta) {
  int idx = blockIdx.x * 256 + threadIdx.x;
  int b = idx / VM1;
  float s = score[idx];
  int f = flag[idx];
  float vi = f ? s : NEG_C;
  float ve = f ? NEG_C : s;
  float fin = beta[b * 2] * expf(vi - stats[b * 4]) / stats[b * 4 + 1]
            + beta[b * 2 + 1] * expf(ve - stats[b * 4 + 2]) / stats[b * 4 + 3];
  score[idx] = fin;
}

// ================================================================ launch
extern "C" void kernel_launch(void* const* d_in, const int* in_sizes, int n_in,
                              void* d_out, int out_size, void* d_ws, size_t ws_size,
                              hipStream_t stream) {
  const float* seq1  = (const float*)d_in[0];
  const float* seq2  = (const float*)d_in[1];
  const int*   mask  = (const int*)d_in[2];
  const int*   iflag = (const int*)d_in[3];
  const float* wih0  = (const float*)d_in[4];
  const float* whh0  = (const float*)d_in[5];
  const float* bih0  = (const float*)d_in[6];
  const float* bhh0  = (const float*)d_in[7];
  const float* wih1  = (const float*)d_in[8];
  const float* whh1  = (const float*)d_in[9];
  const float* bih1  = (const float*)d_in[10];
  const float* bhh1  = (const float*)d_in[11];
  const float* Wq1   = (const float*)d_in[12];
  const float* Wk1   = (const float*)d_in[13];
  const float* Wv1   = (const float*)d_in[14];
  const float* Wk2   = (const float*)d_in[16];
  const float* Wv2   = (const float*)d_in[17];
  const float* Wffn1 = (const float*)d_in[18];
  const float* bffn1 = (const float*)d_in[19];
  const float* Wffn2 = (const float*)d_in[20];
  const float* bffn2 = (const float*)d_in[21];
  const float* Wone  = (const float*)d_in[22];
  const float* bone  = (const float*)d_in[23];
  const float* W3    = (const float*)d_in[24];
  const float* Wtr   = (const float*)d_in[25];
  const float* btr   = (const float*)d_in[26];
  const float* Wt1   = (const float*)d_in[27];
  const float* bt1   = (const float*)d_in[28];
  const float* Wt2   = (const float*)d_in[29];
  const float* memk  = (const float*)d_in[30];
  const float* memv  = (const float*)d_in[31];
  const float* emb1  = (const float*)d_in[32];
  float* out = (float*)d_out;

  // Workspace layout (byte offsets, all 16B-aligned). Total ≈ 214.1 MB.
  char* wsb = (char*)d_ws;
  float*  TAB    = (float*)(wsb + 0);            // 51,200
  int*    lastp  = (int*)  (wsb + 51200);        // 2,048
  float*  srl    = (float*)(wsb + 53248);        // 524,288
  float*  q11    = (float*)(wsb + 577536);       // 524,288
  ushort* whh0b  = (ushort*)(wsb + 1101824);     // 393,216 (bf16 whh, layer 0)
  ushort* whh1b  = (ushort*)(wsb + 1888256);     // 393,216 (bf16 whh, layer 1)
  ushort* wih0b  = (ushort*)(wsb + 2674688);     // 393,216
  ushort* wih1b  = (ushort*)(wsb + 3067904);     // 393,216
  ushort* w7b    = (ushort*)(wsb + 3461120);     // 7 x 131,072
  ushort* bufS   = (ushort*)(wsb + 4378624);     // 13,107,200  seq2b -> ys1b -> se2b
  float*  se1    = (float*)(wsb + 17485824);     // 26,214,400
  ushort* se1b   = (ushort*)(wsb + 43700224);    // 13,107,200
  float*  giQ    = (float*)(wsb + 56807424);     // 78,643,200  gi -> q1|k1|v1 -> tail
  float*  kv2a   = (float*)(wsb + 135450624);    // 26,214,400  k2 -> att1p
  float*  kv2b   = (float*)(wsb + 161665024);    // 26,214,400  v2 -> att2p
  ushort* ao1b   = (ushort*)(wsb + 187879424);   // 13,107,200
  ushort* ao2b   = (ushort*)(wsb + 200986624);   // 13,107,200

  float* gi = giQ;
  float* q1 = giQ;
  float* k1 = giQ + 6553600;
  float* v1 = giQ + 13107200;
  // tail block (reuses giQ after attn2):
  ushort* embB    = (ushort*)giQ;                             // 20,480,000 B
  float*  sesscat = (float*)((char*)giQ + 20480000);          // 1,048,576
  float*  sess2   = (float*)((char*)giQ + 21528576);          // 524,288
  ushort* sess2b  = (ushort*)((char*)giQ + 22052864);         // 262,144
  float*  betab   = (float*)((char*)giQ + 22315008);          // 4,096
  float*  stats   = (float*)((char*)giQ + 22319104);          // 8,192
  float*  bnd     = out + (size_t)Bsz * VM1;                  // boundary output slot

  ushort* Wq1b = w7b;              ushort* Wk1b = w7b + 65536;
  ushort* Wv1b = w7b + 131072;     ushort* Wk2b = w7b + 196608;
  ushort* Wv2b = w7b + 262144;     ushort* Wf1b = w7b + 327680;
  ushort* Wf2b = w7b + 393216;

  // ---- table / last / q1_1 (fp32 path)
  build_tab<<<50, 256, 0, stream>>>(TAB);
  last_srl_kernel<<<Bsz, 256, 0, stream>>>(mask, seq1, lastp, srl);
  gemm_tile<0, 1><<<dim3(4, 4), 256, 0, stream>>>(srl, Wone, bone, q11, 512, 256, 256);
  add_tab0<<<512, 256, 0, stream>>>(q11);

  // ---- weight casts
  cast_f2b_k<<<6400, 256, 0, stream>>>(seq2, bufS, 1638400);
  cast_f2b_k<<<192, 256, 0, stream>>>(wih0, wih0b, 49152);
  cast_f2b_k<<<192, 256, 0, stream>>>(wih1, wih1b, 49152);
  cast_f2b_k<<<192, 256, 0, stream>>>(whh0, whh0b, 49152);
  cast_f2b_k<<<192, 256, 0, stream>>>(whh1, whh1b, 49152);
  Cast7 c7;
  c7.s[0] = Wq1; c7.s[1] = Wk1; c7.s[2] = Wv1; c7.s[3] = Wk2; c7.s[4] = Wv2;
  c7.s[5] = Wffn1; c7.s[6] = Wffn2;
  c7.d[0] = Wq1b; c7.d[1] = Wk1b; c7.d[2] = Wv1b; c7.d[3] = Wk2b; c7.d[4] = Wv2b;
  c7.d[5] = Wf1b; c7.d[6] = Wf2b;
  cast7_k<<<dim3(64, 7), 256, 0, stream>>>(c7);

  // ---- GRU (gi via MFMA, recurrence via reg-resident MFMA)
  mfma_gemm<1, 1><<<dim3(6, 200), 256, 0, stream>>>(bufS, wih0b, bih0, gi, 25600, 768, 256);
  gru_mfma_kernel<<<256, 256, 0, stream>>>(gi, whh0b, bhh0, bufS, nullptr);
  mfma_gemm<1, 1><<<dim3(6, 200), 256, 0, stream>>>(bufS, wih1b, bih1, gi, 25600, 768, 256);
  gru_mfma_kernel<<<256, 256, 0, stream>>>(gi, whh1b, bhh1, bufS, mask);   // -> se2 bf16

  // ---- masked seq1 (fp32 + bf16)
  mask_mul_dual<<<25600, 256, 0, stream>>>(seq1, mask, se1, se1b);

  // ---- projections (MFMA)
  mfma_gemm<0, 0><<<dim3(2, 200), 256, 0, stream>>>(bufS, Wk2b, nullptr, kv2a, 25600, 256, 256);
  mfma_gemm<0, 0><<<dim3(2, 200), 256, 0, stream>>>(bufS, Wv2b, nullptr, kv2b, 25600, 256, 256);
  mfma_gemm<0, 0><<<dim3(2, 200), 256, 0, stream>>>(se1b, Wq1b, nullptr, q1, 25600, 256, 256);
  mfma_gemm<0, 0><<<dim3(2, 200), 256, 0, stream>>>(se1b, Wk1b, nullptr, k1, 25600, 256, 256);
  mfma_gemm<0, 0><<<dim3(2, 200), 256, 0, stream>>>(se1b, Wv1b, nullptr, v1, 25600, 256, 256);
  add_pe3<<<25600, 256, 0, stream>>>(q1, k1, v1, TAB, lastp);

  // ---- attentions (fp32 in, bf16 out)
  attn1_kernel<<<Bsz, 256, 0, stream>>>(q1, k1, v1, mask, ao1b);
  attn2_kernel<<<Bsz, 256, 0, stream>>>(q1, kv2a, kv2b, memk, memv, mask, ao2b);
  mfma_gemm<0, 1><<<dim3(2, 200), 256, 0, stream>>>(ao1b, Wf1b, bffn1, kv2a, 25600, 256, 256);
  mfma_gemm<0, 1><<<dim3(2, 200), 256, 0, stream>>>(ao2b, Wf2b, bffn2, kv2b, 25600, 256, 256);
  relu_add<<<25600, 256, 0, stream>>>(kv2a, kv2b);          // att

  // ---- pooling + session (fp32)
  alpha_sess_kernel<<<Bsz, 256, 0, stream>>>(kv2a, W3, q11, se1, mask, srl, sesscat);
  gemm_tile<0, 1><<<dim3(4, 4), 256, 0, stream>>>(sesscat, Wtr, btr, sess2, 512, 256, 512);
  cast_f2b_k<<<128, 256, 0, stream>>>(sess2, sess2b, 32768);

  // ---- tail gating (fp32) + scoring (MFMA)
  hipMemsetAsync(bnd, 0, 4, stream);
  beta_kernel<<<Bsz, 256, 0, stream>>>(sess2, Wt1, bt1, Wt2, betab, bnd);
  cast_f2b_k<<<10000, 256, 0, stream>>>(emb1 + 256, embB, 2560000);
  mfma_gemm<1, 0><<<dim3(313, 4), 256, 0, stream>>>(sess2b, embB, nullptr, out, 512, VM1, 256);
  score_stats_kernel<<<Bsz, 256, 0, stream>>>(out, iflag, stats);
  final_kernel<<<80000, 256, 0, stream>>>(out, iflag, stats, betab);

  (void)in_sizes; (void)n_in; (void)out_size; (void)ws_size;
}

// Round 4
// 1130.951 us; speedup vs baseline: 2.6324x; 1.2469x over previous
//
#include <hip/hip_runtime.h>
#include <hip/hip_bf16.h>
#include <cstdint>
#include <cstddef>

// Problem dims
#define Bsz 512
#define Nsq 50
#define Hd  256
#define VM1 40000
static constexpr float SCALE_C = 0.0625f;   // 1/sqrt(256)
static constexpr float NEG_C   = -1.0e12f;

typedef __attribute__((ext_vector_type(8))) short bf16x8;
typedef __attribute__((ext_vector_type(4))) float f32x4;

__device__ __forceinline__ float sigmoidf_(float x) { return 1.0f / (1.0f + __expf(-x)); }
__device__ __forceinline__ float tanh_fast(float x) {
  float t = fminf(fmaxf(2.0f * x, -60.0f), 60.0f);
  float e = __expf(t);
  return (e - 1.0f) / (e + 1.0f);
}
__device__ __forceinline__ ushort f2b(float x) {   // fp32 -> bf16 (RNE)
  union { float f; uint32_t u; } c; c.f = x;
  uint32_t r = (c.u + 0x7fffu + ((c.u >> 16) & 1u)) >> 16;
  return (ushort)r;
}

// ---------------------------------------------------------------- TAB (50x256)
__global__ void build_tab(float* __restrict__ TAB) {
  int idx = blockIdx.x * 256 + threadIdx.x;
  int pos = idx >> 8, j = idx & 255;
  int pair = j >> 1;
  float expo = (2.0f * (float)pair) / 256.0f;
  float inv = powf(10000.0f, -expo);
  float ang = (float)pos * inv;
  TAB[idx] = (j & 1) ? cosf(ang) : sinf(ang);
}

// ------------------------------------------------- last[b], sr_l_1 = seq1[b,last]
__global__ __launch_bounds__(256) void last_srl_kernel(const int* __restrict__ mask,
    const float* __restrict__ seq1, int* __restrict__ lastp, float* __restrict__ srl) {
  int b = blockIdx.x, tid = threadIdx.x;
  __shared__ int ls;
  if (tid == 0) {
    int c = 0;
    for (int t = 0; t < Nsq; ++t) c += mask[b * Nsq + t];
    ls = c - 1;
    lastp[b] = c - 1;
  }
  __syncthreads();
  srl[b * Hd + tid] = seq1[((size_t)b * Nsq + ls) * Hd + tid];
}

// ---------------------------------------------------------------- fp32 GEMM (small shapes only)
template <int BT, int BIAS>
__global__ __launch_bounds__(256) void gemm_tile(const float* __restrict__ A,
    const float* __restrict__ B, const float* __restrict__ bias,
    float* __restrict__ C, int M, int N, int K) {
  __shared__ float As[16][132];
  __shared__ float Bs[16][68];
  int bm = blockIdx.y * 128, bn = blockIdx.x * 64;
  int tid = threadIdx.x;
  int tm = (tid >> 4) << 3;
  int tn = (tid & 15) << 2;
  float acc[8][4] = {};
  for (int k0 = 0; k0 < K; k0 += 16) {
#pragma unroll
    for (int u = 0; u < 8; ++u) {
      int i = tid + u * 256;
      int kk = i & 15, m = i >> 4;
      As[kk][m] = A[(size_t)(bm + m) * K + (k0 + kk)];
    }
#pragma unroll
    for (int u = 0; u < 4; ++u) {
      int i = tid + u * 256;
      if (BT) {
        int kk = i & 15, n = i >> 4;
        Bs[kk][n] = B[(size_t)(bn + n) * K + (k0 + kk)];
      } else {
        int n = i & 63, kk = i >> 6;
        Bs[kk][n] = B[(size_t)(k0 + kk) * N + (bn + n)];
      }
    }
    __syncthreads();
#pragma unroll
    for (int kk = 0; kk < 16; ++kk) {
      float a[8], bb[4];
#pragma unroll
      for (int r = 0; r < 8; ++r) a[r] = As[kk][tm + r];
#pragma unroll
      for (int c = 0; c < 4; ++c) bb[c] = Bs[kk][tn + c];
#pragma unroll
      for (int r = 0; r < 8; ++r)
#pragma unroll
        for (int c = 0; c < 4; ++c) acc[r][c] += a[r] * bb[c];
    }
    __syncthreads();
  }
#pragma unroll
  for (int r = 0; r < 8; ++r) {
    size_t row = (size_t)(bm + tm + r) * N + bn;
#pragma unroll
    for (int c = 0; c < 4; ++c) {
      float v = acc[r][c];
      if (BIAS) v += bias[bn + tn + c];
      C[row + tn + c] = v;
    }
  }
}

// ---------------------------------------------------------------- bf16 MFMA GEMM
// C[M,N] fp32 = A_bf[M,K] @ (BT ? B_bf[N,K]^T : B_bf[K,N]) (+bias)
// tile 128x128, BK=32, 256 threads = 4 waves (each 64x64 quadrant, 4x4 frags of 16x16x32).
template <int BT, int BIAS>
__global__ __launch_bounds__(256) void mfma_gemm(const ushort* __restrict__ A,
    const ushort* __restrict__ B, const float* __restrict__ bias,
    float* __restrict__ C, int M, int N, int K) {
  __shared__ ushort Asm[128][40];   // [m][k], +8 pad
  __shared__ ushort Bsm[128][40];   // [n][k]
  int tid = threadIdx.x;
  int bm = blockIdx.y * 128, bn = blockIdx.x * 128;
  int lane = tid & 63, wave = tid >> 6;
  int quad = lane >> 4, l16 = lane & 15;
  int wm = (wave >> 1) * 64, wn = (wave & 1) * 64;
  f32x4 acc[4][4] = {};
  for (int k0 = 0; k0 < K; k0 += 32) {
#pragma unroll
    for (int u = 0; u < 2; ++u) {               // A: 128x32, 16B per thread x2
      int idx = tid + u * 256;
      int r = idx >> 2, kc = (idx & 3) * 8;
      uint4 v = *(const uint4*)(A + (size_t)(bm + r) * K + k0 + kc);
      *(uint4*)&Asm[r][kc] = v;
    }
    if (BT) {
#pragma unroll
      for (int u = 0; u < 2; ++u) {
        int idx = tid + u * 256;
        int r = idx >> 2, kc = (idx & 3) * 8;
        uint4 v = make_uint4(0u, 0u, 0u, 0u);
        if (bn + r < N) v = *(const uint4*)(B + (size_t)(bn + r) * K + k0 + kc);
        *(uint4*)&Bsm[r][kc] = v;
      }
    } else {
#pragma unroll
      for (int u = 0; u < 8; ++u) {             // transpose-stage: 2 n per thread
        int idx = tid + u * 256;
        int n2 = (idx & 63) * 2, kk = idx >> 6;
        uint v = *(const uint*)(B + (size_t)(k0 + kk) * N + bn + n2);
        Bsm[n2][kk] = (ushort)(v & 0xffffu);
        Bsm[n2 + 1][kk] = (ushort)(v >> 16);
      }
    }
    __syncthreads();
    bf16x8 af[4], bfr[4];
#pragma unroll
    for (int f = 0; f < 4; ++f) af[f] = *(const bf16x8*)&Asm[wm + f * 16 + l16][quad * 8];
#pragma unroll
    for (int f = 0; f < 4; ++f) bfr[f] = *(const bf16x8*)&Bsm[wn + f * 16 + l16][quad * 8];
#pragma unroll
    for (int mf = 0; mf < 4; ++mf)
#pragma unroll
      for (int nf = 0; nf < 4; ++nf)
        acc[mf][nf] = __builtin_amdgcn_mfma_f32_16x16x32_bf16(af[mf], bfr[nf], acc[mf][nf], 0, 0, 0);
    __syncthreads();
  }
#pragma unroll
  for (int mf = 0; mf < 4; ++mf) {
#pragma unroll
    for (int r = 0; r < 4; ++r) {
      int row = bm + wm + mf * 16 + quad * 4 + r;
      size_t rowo = (size_t)row * N;
#pragma unroll
      for (int nf = 0; nf < 4; ++nf) {
        int col = bn + wn + nf * 16 + l16;
        if (col < N) {
          float v = acc[mf][nf][r];
          if (BIAS) v += bias[col];
          C[rowo + col] = v;
        }
      }
    }
  }
}

// ---------------------------------------------------------------- casts
__global__ void cast_f2b_k(const float* __restrict__ s, ushort* __restrict__ d, int n4) {
  int i = blockIdx.x * 256 + threadIdx.x;
  if (i >= n4) return;
  const float4 v = ((const float4*)s)[i];
  ushort4 o; o.x = f2b(v.x); o.y = f2b(v.y); o.z = f2b(v.z); o.w = f2b(v.w);
  ((ushort4*)d)[i] = o;
}

struct Cast7 { const float* s[7]; ushort* d[7]; };
__global__ void cast7_k(Cast7 p) {
  int m = blockIdx.y;
  int i = blockIdx.x * 256 + threadIdx.x;
  const float4 v = ((const float4*)p.s[m])[i];
  ushort4 o; o.x = f2b(v.x); o.y = f2b(v.y); o.z = f2b(v.z); o.w = f2b(v.w);
  ((ushort4*)p.d[m])[i] = o;
}

// ---------------------------------------------------------------- misc elementwise
__global__ void add_tab0(float* __restrict__ q) {
  int idx = blockIdx.x * 256 + threadIdx.x;
  q[idx] += (float)(threadIdx.x & 1);         // TAB[0]: sin(0)=0, cos(0)=1
}

__global__ void mask_mul_dual(const float* __restrict__ x, const int* __restrict__ m,
                              float* __restrict__ y, ushort* __restrict__ yb) {
  int idx = blockIdx.x * 256 + threadIdx.x;
  float v = m[idx >> 8] ? x[idx] : 0.0f;
  y[idx] = v;
  yb[idx] = f2b(v);
}

__global__ void add_pe3(float* __restrict__ q, float* __restrict__ k, float* __restrict__ v,
                        const float* __restrict__ TAB, const int* __restrict__ lastp) {
  int idx = blockIdx.x * 256 + threadIdx.x;
  int j = idx & 255, bt = idx >> 8;
  int b = bt / Nsq, t = bt - b * Nsq;
  int d = abs(t - lastp[b]);
  float pe = TAB[d * 256 + j];
  q[idx] += pe; k[idx] += pe; v[idx] += pe;
}

__global__ void relu_add(float* __restrict__ a, const float* __restrict__ b) {
  int idx = blockIdx.x * 256 + threadIdx.x;
  a[idx] = fmaxf(a[idx] + b[idx], 0.0f);
}

// ---------------------------------------------------------------- GRU layer (MFMA, reg-resident weights)
__global__ __launch_bounds__(256, 1) void gru_mfma_kernel(const float* __restrict__ gi,
    const ushort* __restrict__ whhb, const float* __restrict__ bhh,
    ushort* __restrict__ ysb, const int* __restrict__ mask) {
  __shared__ ushort hbf[16][264];   // A-source: [m=sample][k]
  __shared__ float hs[2][256];      // fp32 h carry
  __shared__ float ghs[768][2];     // gh results [n][sample]
  int tid = threadIdx.x;
  int lane = tid & 63, wave = tid >> 6;
  int q = lane >> 4, l16 = lane & 15;
  int s0 = blockIdx.x * 2;

  for (int i = tid; i < 16 * 264; i += 256) ((ushort*)hbf)[i] = 0;
  hs[0][tid] = 0.0f; hs[1][tid] = 0.0f;

  bf16x8 bw[96];
  const ushort* wbase = whhb + (size_t)(wave * 192 + l16) * 256 + q * 8;
#pragma unroll
  for (int f = 0; f < 96; ++f) {
    int nf = f >> 3, kf = f & 7;
    bw[f] = *(const bf16x8*)(wbase + nf * (16 * 256) + kf * 32);
  }

  float bh0 = bhh[tid], bh1 = bhh[256 + tid], bh2 = bhh[512 + tid];
  const float* gib0 = gi + (size_t)s0 * Nsq * 768;
  const float* gib1 = gi + (size_t)(s0 + 1) * Nsq * 768;
  float g00 = gib0[tid], g01 = gib0[256 + tid], g02 = gib0[512 + tid];
  float g10 = gib1[tid], g11 = gib1[256 + tid], g12 = gib1[512 + tid];
  __syncthreads();

  for (int t = 0; t < Nsq; ++t) {
    int tn = (t + 1 < Nsq) ? t + 1 : t;
    float p00 = gib0[tn * 768 + tid], p01 = gib0[tn * 768 + 256 + tid], p02 = gib0[tn * 768 + 512 + tid];
    float p10 = gib1[tn * 768 + tid], p11 = gib1[tn * 768 + 256 + tid], p12 = gib1[tn * 768 + 512 + tid];

    bf16x8 a[8];
#pragma unroll
    for (int kf = 0; kf < 8; ++kf) a[kf] = *(const bf16x8*)&hbf[l16][kf * 32 + q * 8];
    f32x4 acc[12] = {};
#pragma unroll
    for (int kf = 0; kf < 8; ++kf)
#pragma unroll
      for (int nf = 0; nf < 12; ++nf)
        acc[nf] = __builtin_amdgcn_mfma_f32_16x16x32_bf16(a[kf], bw[nf * 8 + kf], acc[nf], 0, 0, 0);
    if (q == 0) {
#pragma unroll
      for (int nf = 0; nf < 12; ++nf) {
        int n = wave * 192 + nf * 16 + l16;
        ghs[n][0] = acc[nf][0];
        ghs[n][1] = acc[nf][1];
      }
    }
    __syncthreads();

    {
      float rr = sigmoidf_(g00 + ghs[tid][0] + bh0);
      float zz = sigmoidf_(g01 + ghs[256 + tid][0] + bh1);
      float nn = tanh_fast(g02 + rr * (ghs[512 + tid][0] + bh2));
      // NOTE: reference is tanh(inn + r*(hn)) with hn = h@whh_n^T + bhh_n
      float h2 = (1.0f - zz) * nn + zz * hs[0][tid];
      hs[0][tid] = h2;
      hbf[0][tid] = f2b(h2);
      float ov = h2;
      if (mask) ov = mask[s0 * Nsq + t] ? h2 : 0.0f;
      ysb[((size_t)s0 * Nsq + t) * 256 + tid] = f2b(ov);
    }
    {
      float rr = sigmoidf_(g10 + ghs[tid][1] + bh0);
      float zz = sigmoidf_(g11 + ghs[256 + tid][1] + bh1);
      float nn = tanh_fast(g12 + rr * (ghs[512 + tid][1] + bh2));
      float h2 = (1.0f - zz) * nn + zz * hs[1][tid];
      hs[1][tid] = h2;
      hbf[1][tid] = f2b(h2);
      float ov = h2;
      if (mask) ov = mask[(s0 + 1) * Nsq + t] ? h2 : 0.0f;
      ysb[((size_t)(s0 + 1) * Nsq + t) * 256 + tid] = f2b(ov);
    }
    g00 = p00; g01 = p01; g02 = p02;
    g10 = p10; g11 = p11; g12 = p12;
    __syncthreads();
  }
}

// ---------------------------------------------------------------- MFMA attention
// One block per batch sample, 256 threads = 4 waves.
// S = Q[50,256] K^T[*,256] via MFMA; masked softmax; O = P V via MFMA.
// NMEM = 0 (attn1) or 8 (attn2: mem rows prepended). Output bf16, mask-zeroed.
template <int NMEM>
__global__ __launch_bounds__(256) void attn_mfma(const float* __restrict__ q1,
    const float* __restrict__ kseq, const float* __restrict__ vseq,
    const float* __restrict__ kmem, const float* __restrict__ vmem,
    const int* __restrict__ mask, ushort* __restrict__ out) {
  constexpr int NK = NMEM + Nsq;            // valid K/V rows (50 or 58)
  __shared__ ushort KV[64][264];            // Q -> K -> V staging (bf16)
  __shared__ float Ss[64][66];              // scores fp32
  __shared__ ushort Ps[64][72];             // probabilities bf16
  __shared__ int msk[64];
  int tid = threadIdx.x;
  int lane = tid & 63, wave = tid >> 6;
  int quad = lane >> 4, l16 = lane & 15;
  int b = blockIdx.x;

  if (tid < 64) msk[tid] = (tid < Nsq) ? mask[b * Nsq + tid] : 0;

  // ---- stage Q (rows t<50, else 0)
#pragma unroll
  for (int it = 0; it < 16; ++it) {
    int idx = tid + it * 256;
    int r = idx >> 6, c4 = (idx & 63) * 4;
    float4 v = make_float4(0.f, 0.f, 0.f, 0.f);
    if (r < Nsq) v = *(const float4*)(q1 + ((size_t)(b * Nsq + r)) * 256 + c4);
    ushort4 o; o.x = f2b(v.x); o.y = f2b(v.y); o.z = f2b(v.z); o.w = f2b(v.w);
    *(ushort4*)&KV[r][c4] = o;
  }
  __syncthreads();
  // Q A-frags: wave w owns t rows [w*16, w*16+16)
  bf16x8 qa[8];
#pragma unroll
  for (int kf = 0; kf < 8; ++kf)
    qa[kf] = *(const bf16x8*)&KV[wave * 16 + l16][kf * 32 + quad * 8];
  __syncthreads();

  // ---- stage K (rows: [0,NMEM) mem, [NMEM,NK) seq, else 0)
#pragma unroll
  for (int it = 0; it < 16; ++it) {
    int idx = tid + it * 256;
    int r = idx >> 6, c4 = (idx & 63) * 4;
    float4 v = make_float4(0.f, 0.f, 0.f, 0.f);
    if (r < NK) {
      const float* src = (NMEM > 0 && r < NMEM)
          ? (kmem + (size_t)r * 256 + c4)
          : (kseq + ((size_t)(b * Nsq + (r - NMEM))) * 256 + c4);
      v = *(const float4*)src;
    }
    ushort4 o; o.x = f2b(v.x); o.y = f2b(v.y); o.z = f2b(v.z); o.w = f2b(v.w);
    *(ushort4*)&KV[r][c4] = o;
  }
  __syncthreads();

  // ---- S = Q K^T  (wave w: rows [w*16, +16) x all 64 cols)
  {
    f32x4 acc[4] = {};
#pragma unroll
    for (int kf = 0; kf < 8; ++kf) {
#pragma unroll
      for (int nf = 0; nf < 4; ++nf) {
        bf16x8 bf = *(const bf16x8*)&KV[nf * 16 + l16][kf * 32 + quad * 8];
        acc[nf] = __builtin_amdgcn_mfma_f32_16x16x32_bf16(qa[kf], bf, acc[nf], 0, 0, 0);
      }
    }
#pragma unroll
    for (int nf = 0; nf < 4; ++nf)
#pragma unroll
      for (int r = 0; r < 4; ++r)
        Ss[wave * 16 + quad * 4 + r][nf * 16 + l16] = acc[nf][r];
  }
  __syncthreads();

  // ---- stage V over K region (all threads) ...
#pragma unroll
  for (int it = 0; it < 16; ++it) {
    int idx = tid + it * 256;
    int r = idx >> 6, c4 = (idx & 63) * 4;
    float4 v = make_float4(0.f, 0.f, 0.f, 0.f);
    if (r < NK) {
      const float* src = (NMEM > 0 && r < NMEM)
          ? (vmem + (size_t)r * 256 + c4)
          : (vseq + ((size_t)(b * Nsq + (r - NMEM))) * 256 + c4);
      v = *(const float4*)src;
    }
    ushort4 o; o.x = f2b(v.x); o.y = f2b(v.y); o.z = f2b(v.z); o.w = f2b(v.w);
    *(ushort4*)&KV[r][c4] = o;
  }
  // ... while lane-per-row softmax runs on wave 0
  if (tid < 64) {
    int t = tid;
    if (t < Nsq) {
      float m = -1e30f;
      for (int j = 0; j < NK; ++j) {
        bool ok = (j < NMEM) || (((j - NMEM) <= t) && (msk[j - NMEM] != 0));
        if (ok) m = fmaxf(m, Ss[t][j] * SCALE_C);
      }
      float sum = 0.0f;
      for (int j = 0; j < NK; ++j) {
        bool ok = (j < NMEM) || (((j - NMEM) <= t) && (msk[j - NMEM] != 0));
        if (ok) sum += __expf(Ss[t][j] * SCALE_C - m);
      }
      float inv = 1.0f / sum;
      for (int j = 0; j < 64; ++j) {
        float p = 0.0f;
        if (j < NK) {
          bool ok = (j < NMEM) || (((j - NMEM) <= t) && (msk[j - NMEM] != 0));
          if (ok) p = __expf(Ss[t][j] * SCALE_C - m) * inv;
        }
        Ps[t][j] = f2b(p);
      }
    } else {
      for (int j = 0; j < 64; ++j) Ps[t][j] = 0;
    }
  }
  __syncthreads();

  // ---- O = P V  (wave w: all 64 t-rows x h in [w*64, +64))
  {
    f32x4 o[4][4] = {};
#pragma unroll
    for (int kf = 0; kf < 2; ++kf) {
      bf16x8 pa[4];
#pragma unroll
      for (int mf = 0; mf < 4; ++mf)
        pa[mf] = *(const bf16x8*)&Ps[mf * 16 + l16][kf * 32 + quad * 8];
#pragma unroll
      for (int nf = 0; nf < 4; ++nf) {
        int h = wave * 64 + nf * 16 + l16;
        ushort e0 = KV[kf * 32 + quad * 8 + 0][h];
        ushort e1 = KV[kf * 32 + quad * 8 + 1][h];
        ushort e2 = KV[kf * 32 + quad * 8 + 2][h];
        ushort e3 = KV[kf * 32 + quad * 8 + 3][h];
        ushort e4 = KV[kf * 32 + quad * 8 + 4][h];
        ushort e5 = KV[kf * 32 + quad * 8 + 5][h];
        ushort e6 = KV[kf * 32 + quad * 8 + 6][h];
        ushort e7 = KV[kf * 32 + quad * 8 + 7][h];
        bf16x8 vb = {(short)e0, (short)e1, (short)e2, (short)e3,
                     (short)e4, (short)e5, (short)e6, (short)e7};
#pragma unroll
        for (int mf = 0; mf < 4; ++mf)
          o[mf][nf] = __builtin_amdgcn_mfma_f32_16x16x32_bf16(pa[mf], vb, o[mf][nf], 0, 0, 0);
      }
    }
#pragma unroll
    for (int mf = 0; mf < 4; ++mf) {
#pragma unroll
      for (int r = 0; r < 4; ++r) {
        int t = mf * 16 + quad * 4 + r;
        if (t < Nsq) {
          int zero = (msk[t] == 0);
#pragma unroll
          for (int nf = 0; nf < 4; ++nf) {
            int h = wave * 64 + nf * 16 + l16;
            float val = zero ? 0.0f : o[mf][nf][r];
            out[((size_t)(b * Nsq + t)) * 256 + h] = f2b(val);
          }
        }
      }
    }
  }
}

// ---------------------------------------------------------------- alpha + sess (→ sesscat)
__global__ __launch_bounds__(256) void alpha_sess_kernel(const float* __restrict__ att,
    const float* __restrict__ W3, const float* __restrict__ q11,
    const float* __restrict__ se1, const int* __restrict__ mask,
    const float* __restrict__ srl, float* __restrict__ sesscat) {
  int b = blockIdx.x, tid = threadIdx.x;
  __shared__ float red[256];
  __shared__ float ash[50];
  red[tid] = q11[b * Hd + tid] * W3[256 + tid];
  __syncthreads();
  for (int s = 128; s; s >>= 1) { if (tid < s) red[tid] += red[tid + s]; __syncthreads(); }
  float cq = red[0];
  float aval = 0.0f;
  if (tid < 50) {
    float s = cq;
    const float* ar = att + ((size_t)b * Nsq + tid) * Hd;
    for (int hh = 0; hh < 256; ++hh) s += ar[hh] * W3[hh];
    aval = mask[b * Nsq + tid] ? s : NEG_C;
  }
  if (tid < 64) {
    float s = (tid < 50) ? aval : NEG_C;
    float m = s;
    for (int off = 32; off; off >>= 1) m = fmaxf(m, __shfl_xor(m, off));
    float e = expf(s - m);
    float sum = e;
    for (int off = 32; off; off >>= 1) sum += __shfl_xor(sum, off);
    if (tid < 50) ash[tid] = e / sum;
  }
  __syncthreads();
  float acc = 0.0f;
  const float* se = se1 + (size_t)b * Nsq * Hd;
  for (int t = 0; t < Nsq; ++t) acc += ash[t] * se[t * 256 + tid];
  sesscat[(size_t)b * 512 + tid] = acc;
  sesscat[(size_t)b * 512 + 256 + tid] = srl[b * Hd + tid];
}

// ---------------------------------------------------------------- beta + boundary (fp32)
__global__ __launch_bounds__(256) void beta_kernel(const float* __restrict__ sess2,
    const float* __restrict__ Wt1, const float* __restrict__ bt1,
    const float* __restrict__ Wt2, float* __restrict__ beta, float* __restrict__ bnd) {
  int b = blockIdx.x, tid = threadIdx.x;
  __shared__ float xs[256];
  __shared__ float r0[256], r1[256];
  xs[tid] = sess2[b * Hd + tid];
  __syncthreads();
  float hsum = bt1[tid];
  for (int k = 0; k < 256; ++k) hsum += xs[k] * Wt1[k * 256 + tid];
  float hid = fmaxf(hsum, 0.0f);
  r0[tid] = hid * Wt2[tid * 2 + 0];
  r1[tid] = hid * Wt2[tid * 2 + 1];
  __syncthreads();
  for (int s = 128; s; s >>= 1) {
    if (tid < s) { r0[tid] += r0[tid + s]; r1[tid] += r1[tid + s]; }
    __syncthreads();
  }
  if (tid == 0) {
    float t0 = r0[0], t1 = r1[0];
    float m = fmaxf(t0, t1);
    float e0 = expf(t0 - m), e1 = expf(t1 - m);
    float bb0 = e0 / (e0 + e1), bb1 = e1 / (e0 + e1);
    beta[b * 2] = bb0; beta[b * 2 + 1] = bb1;
    atomicAdd(bnd, fabsf(bb0 - bb1) * (1.0f / 512.0f));
  }
}

// ---------------------------------------------------------------- score softmax stats
__global__ __launch_bounds__(256) void score_stats_kernel(const float* __restrict__ score,
    const int* __restrict__ flag, float* __restrict__ stats) {
  int b = blockIdx.x, tid = threadIdx.x;
  float mi = -INFINITY, si = 0.0f, me = -INFINITY, se = 0.0f;
  const float* sr = score + (size_t)b * VM1;
  const int* fr = flag + (size_t)b * VM1;
  for (int i = tid; i < VM1; i += 256) {
    float s = sr[i];
    int f = fr[i];
    float vi = f ? s : NEG_C;
    float ve = f ? NEG_C : s;
    float mni = fmaxf(mi, vi); si = si * expf(mi - mni) + expf(vi - mni); mi = mni;
    float mne = fmaxf(me, ve); se = se * expf(me - mne) + expf(ve - mne); me = mne;
  }
  __shared__ float red[256];
  red[tid] = mi; __syncthreads();
  for (int s = 128; s; s >>= 1) { if (tid < s) red[tid] = fmaxf(red[tid], red[tid + s]); __syncthreads(); }
  float Mi = red[0]; __syncthreads();
  red[tid] = si * expf(mi - Mi); __syncthreads();
  for (int s = 128; s; s >>= 1) { if (tid < s) red[tid] += red[tid + s]; __syncthreads(); }
  float Si = red[0]; __syncthreads();
  red[tid] = me; __syncthreads();
  for (int s = 128; s; s >>= 1) { if (tid < s) red[tid] = fmaxf(red[tid], red[tid + s]); __syncthreads(); }
  float Me = red[0]; __syncthreads();
  red[tid] = se * expf(me - Me); __syncthreads();
  for (int s = 128; s; s >>= 1) { if (tid < s) red[tid] += red[tid + s]; __syncthreads(); }
  float Se = red[0];
  if (tid == 0) { stats[b * 4] = Mi; stats[b * 4 + 1] = Si; stats[b * 4 + 2] = Me; stats[b * 4 + 3] = Se; }
}

// ---------------------------------------------------------------- final (in-place on score)
__global__ void final_kernel(float* __restrict__ score, const int* __restrict__ flag,
                             const float* __restrict__ stats, const float* __restrict__ beta) {
  int idx = blockIdx.x * 256 + threadIdx.x;
  int b = idx / VM1;
  float s = score[idx];
  int f = flag[idx];
  float vi = f ? s : NEG_C;
  float ve = f ? NEG_C : s;
  float fin = beta[b * 2] * expf(vi - stats[b * 4]) / stats[b * 4 + 1]
            + beta[b * 2 + 1] * expf(ve - stats[b * 4 + 2]) / stats[b * 4 + 3];
  score[idx] = fin;
}

// ================================================================ launch
extern "C" void kernel_launch(void* const* d_in, const int* in_sizes, int n_in,
                              void* d_out, int out_size, void* d_ws, size_t ws_size,
                              hipStream_t stream) {
  const float* seq1  = (const float*)d_in[0];
  const float* seq2  = (const float*)d_in[1];
  const int*   mask  = (const int*)d_in[2];
  const int*   iflag = (const int*)d_in[3];
  const float* wih0  = (const float*)d_in[4];
  const float* whh0  = (const float*)d_in[5];
  const float* bih0  = (const float*)d_in[6];
  const float* bhh0  = (const float*)d_in[7];
  const float* wih1  = (const float*)d_in[8];
  const float* whh1  = (const float*)d_in[9];
  const float* bih1  = (const float*)d_in[10];
  const float* bhh1  = (const float*)d_in[11];
  const float* Wq1   = (const float*)d_in[12];
  const float* Wk1   = (const float*)d_in[13];
  const float* Wv1   = (const float*)d_in[14];
  const float* Wk2   = (const float*)d_in[16];
  const float* Wv2   = (const float*)d_in[17];
  const float* Wffn1 = (const float*)d_in[18];
  const float* bffn1 = (const float*)d_in[19];
  const float* Wffn2 = (const float*)d_in[20];
  const float* bffn2 = (const float*)d_in[21];
  const float* Wone  = (const float*)d_in[22];
  const float* bone  = (const float*)d_in[23];
  const float* W3    = (const float*)d_in[24];
  const float* Wtr   = (const float*)d_in[25];
  const float* btr   = (const float*)d_in[26];
  const float* Wt1   = (const float*)d_in[27];
  const float* bt1   = (const float*)d_in[28];
  const float* Wt2   = (const float*)d_in[29];
  const float* memk  = (const float*)d_in[30];
  const float* memv  = (const float*)d_in[31];
  const float* emb1  = (const float*)d_in[32];
  float* out = (float*)d_out;

  // Workspace layout (byte offsets, all 16B-aligned). Total ≈ 214.1 MB.
  char* wsb = (char*)d_ws;
  float*  TAB    = (float*)(wsb + 0);            // 51,200
  int*    lastp  = (int*)  (wsb + 51200);        // 2,048
  float*  srl    = (float*)(wsb + 53248);        // 524,288
  float*  q11    = (float*)(wsb + 577536);       // 524,288
  ushort* whh0b  = (ushort*)(wsb + 1101824);     // 393,216 (bf16 whh, layer 0)
  ushort* whh1b  = (ushort*)(wsb + 1888256);     // 393,216 (bf16 whh, layer 1)
  ushort* wih0b  = (ushort*)(wsb + 2674688);     // 393,216
  ushort* wih1b  = (ushort*)(wsb + 3067904);     // 393,216
  ushort* w7b    = (ushort*)(wsb + 3461120);     // 7 x 131,072
  ushort* bufS   = (ushort*)(wsb + 4378624);     // 13,107,200  seq2b -> ys1b -> se2b
  float*  se1    = (float*)(wsb + 17485824);     // 26,214,400
  ushort* se1b   = (ushort*)(wsb + 43700224);    // 13,107,200
  float*  giQ    = (float*)(wsb + 56807424);     // 78,643,200  gi -> q1|k1|v1 -> tail
  float*  kv2a   = (float*)(wsb + 135450624);    // 26,214,400  k2 -> att1p
  float*  kv2b   = (float*)(wsb + 161665024);    // 26,214,400  v2 -> att2p
  ushort* ao1b   = (ushort*)(wsb + 187879424);   // 13,107,200
  ushort* ao2b   = (ushort*)(wsb + 200986624);   // 13,107,200

  float* gi = giQ;
  float* q1 = giQ;
  float* k1 = giQ + 6553600;
  float* v1 = giQ + 13107200;
  // tail block (reuses giQ after attn2):
  ushort* embB    = (ushort*)giQ;                             // 20,480,000 B
  float*  sesscat = (float*)((char*)giQ + 20480000);          // 1,048,576
  float*  sess2   = (float*)((char*)giQ + 21528576);          // 524,288
  ushort* sess2b  = (ushort*)((char*)giQ + 22052864);         // 262,144
  float*  betab   = (float*)((char*)giQ + 22315008);          // 4,096
  float*  stats   = (float*)((char*)giQ + 22319104);          // 8,192
  float*  bnd     = out + (size_t)Bsz * VM1;                  // boundary output slot

  ushort* Wq1b = w7b;              ushort* Wk1b = w7b + 65536;
  ushort* Wv1b = w7b + 131072;     ushort* Wk2b = w7b + 196608;
  ushort* Wv2b = w7b + 262144;     ushort* Wf1b = w7b + 327680;
  ushort* Wf2b = w7b + 393216;

  // ---- table / last / q1_1 (fp32 path)
  build_tab<<<50, 256, 0, stream>>>(TAB);
  last_srl_kernel<<<Bsz, 256, 0, stream>>>(mask, seq1, lastp, srl);
  gemm_tile<0, 1><<<dim3(4, 4), 256, 0, stream>>>(srl, Wone, bone, q11, 512, 256, 256);
  add_tab0<<<512, 256, 0, stream>>>(q11);

  // ---- weight casts
  cast_f2b_k<<<6400, 256, 0, stream>>>(seq2, bufS, 1638400);
  cast_f2b_k<<<192, 256, 0, stream>>>(wih0, wih0b, 49152);
  cast_f2b_k<<<192, 256, 0, stream>>>(wih1, wih1b, 49152);
  cast_f2b_k<<<192, 256, 0, stream>>>(whh0, whh0b, 49152);
  cast_f2b_k<<<192, 256, 0, stream>>>(whh1, whh1b, 49152);
  Cast7 c7;
  c7.s[0] = Wq1; c7.s[1] = Wk1; c7.s[2] = Wv1; c7.s[3] = Wk2; c7.s[4] = Wv2;
  c7.s[5] = Wffn1; c7.s[6] = Wffn2;
  c7.d[0] = Wq1b; c7.d[1] = Wk1b; c7.d[2] = Wv1b; c7.d[3] = Wk2b; c7.d[4] = Wv2b;
  c7.d[5] = Wf1b; c7.d[6] = Wf2b;
  cast7_k<<<dim3(64, 7), 256, 0, stream>>>(c7);

  // ---- GRU (gi via MFMA, recurrence via reg-resident MFMA)
  mfma_gemm<1, 1><<<dim3(6, 200), 256, 0, stream>>>(bufS, wih0b, bih0, gi, 25600, 768, 256);
  gru_mfma_kernel<<<256, 256, 0, stream>>>(gi, whh0b, bhh0, bufS, nullptr);
  mfma_gemm<1, 1><<<dim3(6, 200), 256, 0, stream>>>(bufS, wih1b, bih1, gi, 25600, 768, 256);
  gru_mfma_kernel<<<256, 256, 0, stream>>>(gi, whh1b, bhh1, bufS, mask);   // -> se2 bf16

  // ---- masked seq1 (fp32 + bf16)
  mask_mul_dual<<<25600, 256, 0, stream>>>(seq1, mask, se1, se1b);

  // ---- projections (MFMA)
  mfma_gemm<0, 0><<<dim3(2, 200), 256, 0, stream>>>(bufS, Wk2b, nullptr, kv2a, 25600, 256, 256);
  mfma_gemm<0, 0><<<dim3(2, 200), 256, 0, stream>>>(bufS, Wv2b, nullptr, kv2b, 25600, 256, 256);
  mfma_gemm<0, 0><<<dim3(2, 200), 256, 0, stream>>>(se1b, Wq1b, nullptr, q1, 25600, 256, 256);
  mfma_gemm<0, 0><<<dim3(2, 200), 256, 0, stream>>>(se1b, Wk1b, nullptr, k1, 25600, 256, 256);
  mfma_gemm<0, 0><<<dim3(2, 200), 256, 0, stream>>>(se1b, Wv1b, nullptr, v1, 25600, 256, 256);
  add_pe3<<<25600, 256, 0, stream>>>(q1, k1, v1, TAB, lastp);

  // ---- attentions (MFMA, fp32 in, bf16 out)
  attn_mfma<0><<<Bsz, 256, 0, stream>>>(q1, k1, v1, nullptr, nullptr, mask, ao1b);
  attn_mfma<8><<<Bsz, 256, 0, stream>>>(q1, kv2a, kv2b, memk, memv, mask, ao2b);
  mfma_gemm<0, 1><<<dim3(2, 200), 256, 0, stream>>>(ao1b, Wf1b, bffn1, kv2a, 25600, 256, 256);
  mfma_gemm<0, 1><<<dim3(2, 200), 256, 0, stream>>>(ao2b, Wf2b, bffn2, kv2b, 25600, 256, 256);
  relu_add<<<25600, 256, 0, stream>>>(kv2a, kv2b);          // att

  // ---- pooling + session (fp32)
  alpha_sess_kernel<<<Bsz, 256, 0, stream>>>(kv2a, W3, q11, se1, mask, srl, sesscat);
  gemm_tile<0, 1><<<dim3(4, 4), 256, 0, stream>>>(sesscat, Wtr, btr, sess2, 512, 256, 512);
  cast_f2b_k<<<128, 256, 0, stream>>>(sess2, sess2b, 32768);

  // ---- tail gating (fp32) + scoring (MFMA)
  hipMemsetAsync(bnd, 0, 4, stream);
  beta_kernel<<<Bsz, 256, 0, stream>>>(sess2, Wt1, bt1, Wt2, betab, bnd);
  cast_f2b_k<<<10000, 256, 0, stream>>>(emb1 + 256, embB, 2560000);
  mfma_gemm<1, 0><<<dim3(313, 4), 256, 0, stream>>>(sess2b, embB, nullptr, out, 512, VM1, 256);
  score_stats_kernel<<<Bsz, 256, 0, stream>>>(out, iflag, stats);
  final_kernel<<<80000, 256, 0, stream>>>(out, iflag, stats, betab);

  (void)in_sizes; (void)n_in; (void)out_size; (void)ws_size;
}